// Round 2
// baseline (1287.259 us; speedup 1.0000x reference)
//
#include <hip/hip_runtime.h>
#include <math.h>

#define L 1024
#define NB 8
#define D 768
#define NEGV (-9.0e15f)
#define SCALE 0.036084391824351615f  // 1/sqrt(768)

typedef unsigned short u16;

__device__ __forceinline__ float b2f(u16 u) {
    union { unsigned int i; float f; } v; v.i = ((unsigned int)u) << 16; return v.f;
}
__device__ __forceinline__ u16 f2b(float f) {
    union { float fv; unsigned int i; } v; v.fv = f;
    unsigned int x = v.i;
    x += 0x7fffu + ((x >> 16) & 1u);   // RNE
    return (u16)(x >> 16);
}

template<int F32>
__device__ __forceinline__ float4 ld4(const void* p, size_t idx) {
    if (F32) return *(const float4*)((const float*)p + idx);
    ushort4 v = *(const ushort4*)((const u16*)p + idx);
    return make_float4(b2f(v.x), b2f(v.y), b2f(v.z), b2f(v.w));
}
template<int F32>
__device__ __forceinline__ float ld1(const void* p, size_t idx) {
    if (F32) return ((const float*)p)[idx];
    return b2f(((const u16*)p)[idx]);
}
__device__ __forceinline__ int ldid(const int* p, size_t idx, int is64) {
    return is64 ? p[idx * 2] : p[idx];
}

// ---------------- workspace layout (bytes) ----------------
#define WS_FLAG  ((size_t)0)          // 2 ints
#define WS_SEP   ((size_t)64)         // NB int
#define WS_C0    ((size_t)128)        // 3 f32
#define WS_Z0    ((size_t)192)        // 3*768 f32
#define WS_W1    ((size_t)9472)       // 3*768 f32
#define WS_GATE  ((size_t)18752)      // NB*L f32
#define WS_CSUP  (WS_GATE + (size_t)NB*L*4)
#define WS_CREP  (WS_CSUP + (size_t)NB*L*4)
#define WS_AF    (WS_CREP + (size_t)NB*L*4)
#define WS_WREP  (WS_AF   + (size_t)NB*D*4)
#define WS_WSUP  (WS_WREP + (size_t)NB*D*4)
#define WS_H     (WS_WSUP + (size_t)NB*D*4)
#define WS_ALOG  (WS_H    + (size_t)NB*D*4)
#define WS_T     (WS_ALOG + (size_t)NB*L*4)        // 3*NB*512 f32
#define WS_M     ((size_t)524288)                  // 3*768*768 bf16 = 3.54 MB
#define WS_Z     ((size_t)4194304)                 // 3*NB*512*768 bf16 = 18.9 MB
#define WS_SSUP  ((size_t)23068672)                // NB*512*1024 bf16 = 8.39 MB
#define WS_SCMB  ((size_t)31457280)                // same; end ~39.8 MB

struct PP { const void* W[6]; const void* b[6]; };

// ---------------- detect dtypes ----------------
__global__ __launch_bounds__(128) void kdetect(const void* x, const void* ids, int* flag) {
    __shared__ int cnt[2];
    int tid = threadIdx.x;
    if (tid == 0) { cnt[0] = 0; cnt[1] = 0; }
    __syncthreads();
    if (tid < 64) {
        u16 u = ((const u16*)x)[tid * 2];       // even u16 words
        int e = (u >> 7) & 0xFF;
        if (e >= 100 && e <= 140) atomicAdd(&cnt[0], 1);
    } else {
        int v = ((const int*)ids)[(tid - 64) * 2 + 1];  // odd int32 words
        if (v != 0) atomicAdd(&cnt[1], 1);
    }
    __syncthreads();
    if (tid == 0) {
        flag[0] = (cnt[0] < 32) ? 1 : 0;   // 1 => floats are f32
        flag[1] = (cnt[1] == 0) ? 1 : 0;   // 1 => ids are int64
    }
}

// ---------------- K0a: a_logits = x @ Wa + ba ----------------
template<int F32> __device__ void k0a_body(const void* x, const void* Wa,
        const void* ba, float* alog, float* was) {
    int tid = threadIdx.x;
    for (int i = tid; i < D; i += 256) was[i] = ld1<F32>(Wa, i);
    __syncthreads();
    int row = blockIdx.x * 64 + (tid >> 2);
    int sub = tid & 3;
    float acc = 0.f;
    for (int i = 0; i < 48; ++i) {
        int k = i * 16 + sub * 4;
        float4 xv = ld4<F32>(x, (size_t)row * D + k);
        acc += xv.x * was[k] + xv.y * was[k + 1] + xv.z * was[k + 2] + xv.w * was[k + 3];
    }
    acc += __shfl_xor(acc, 1);
    acc += __shfl_xor(acc, 2);
    if (sub == 0) alog[row] = acc + ld1<F32>(ba, 0);
}
__global__ __launch_bounds__(256) void k0a(const void* x, const void* Wa,
        const void* ba, float* alog, const int* flag) {
    __shared__ float was[D];
    if (flag[0]) k0a_body<1>(x, Wa, ba, alog, was);
    else         k0a_body<0>(x, Wa, ba, alog, was);
}

// ---------------- K0b: sep, gate softmax, zero accumulators ----------------
__global__ __launch_bounds__(256) void k0b(const int* __restrict__ ids,
        const int* __restrict__ padp, const float* __restrict__ alog,
        float* __restrict__ gate, int* __restrict__ sepArr,
        float* __restrict__ csup, float* __restrict__ crep,
        float* __restrict__ af, float* __restrict__ wrep, float* __restrict__ wsup,
        const int* __restrict__ flag) {
    __shared__ float red[256];
    __shared__ int sepSh;
    int is64 = flag[1];
    int b = blockIdx.x, tid = threadIdx.x;
    int pad = padp[0];
    int cnt = 0;
    for (int l = tid; l < L; l += 256) cnt += (ldid(ids, (size_t)b * L + l, is64) != pad) ? 1 : 0;
    red[tid] = (float)cnt; __syncthreads();
    for (int s = 128; s > 0; s >>= 1) { if (tid < s) red[tid] += red[tid + s]; __syncthreads(); }
    if (tid == 0) {
        int vl = (int)red[0];
        int sep = vl / 2; if (sep < 1) sep = 1; if (sep > L - 2) sep = L - 2;
        sepSh = sep; sepArr[b] = sep;
    }
    __syncthreads();
    int sep = sepSh;
    float lv[4]; int lidx[4];
    float mx = -3.4e38f;
    for (int u = 0; u < 4; ++u) {
        int l = tid + u * 256; lidx[u] = l;
        bool fm = (l < sep) && (ldid(ids, (size_t)b * L + l, is64) != pad);
        float v = fm ? alog[b * L + l] : NEGV;
        lv[u] = v; mx = fmaxf(mx, v);
    }
    red[tid] = mx; __syncthreads();
    for (int s = 128; s > 0; s >>= 1) { if (tid < s) red[tid] = fmaxf(red[tid], red[tid + s]); __syncthreads(); }
    mx = red[0]; __syncthreads();
    float se = 0.f;
    for (int u = 0; u < 4; ++u) { lv[u] = expf(lv[u] - mx); se += lv[u]; }
    red[tid] = se; __syncthreads();
    for (int s = 128; s > 0; s >>= 1) { if (tid < s) red[tid] += red[tid + s]; __syncthreads(); }
    float den = fmaxf(red[0], 1e-30f); __syncthreads();
    float gs = 0.f; float gv[4];
    for (int u = 0; u < 4; ++u) {
        int l = lidx[u];
        bool fm = (l < sep) && (ldid(ids, (size_t)b * L + l, is64) != pad);
        float p = lv[u] / den;
        gv[u] = fm ? p : 0.f;
        gs += gv[u];
    }
    red[tid] = gs; __syncthreads();
    for (int s = 128; s > 0; s >>= 1) { if (tid < s) red[tid] += red[tid + s]; __syncthreads(); }
    gs = red[0];
    float inv = 1.f / fmaxf(gs, 1e-8f);
    for (int u = 0; u < 4; ++u) gate[b * L + lidx[u]] = gv[u] * inv;
    for (int l = tid; l < L; l += 256) { csup[b * L + l] = 0.f; crep[b * L + l] = 0.f; }
    for (int i = tid; i < D; i += 256) { af[b * D + i] = 0.f; wrep[b * D + i] = 0.f; wsup[b * D + i] = 0.f; }
}

// ---------------- kM: M_p = Wq_p @ Wk_p^T  (bf16 out) ----------------
template<int F32> __device__ void kM_body(const void* Wq, const void* Wk, u16* Mb,
        float (*Aq)[17], float (*Ak)[17]) {
    int a0 = blockIdx.y * 64, b0 = blockIdx.x * 64;
    int tid = threadIdx.x, tx = tid & 15, ty = tid >> 4;
    int lr = tid >> 2, lkc = (tid & 3) << 2;
    float acc[4][4];
    #pragma unroll
    for (int i = 0; i < 4; ++i)
        #pragma unroll
        for (int j = 0; j < 4; ++j) acc[i][j] = 0.f;
    for (int k0 = 0; k0 < D; k0 += 16) {
        float4 a = ld4<F32>(Wq, (size_t)(a0 + lr) * D + k0 + lkc);
        Aq[lr][lkc] = a.x; Aq[lr][lkc + 1] = a.y; Aq[lr][lkc + 2] = a.z; Aq[lr][lkc + 3] = a.w;
        float4 c = ld4<F32>(Wk, (size_t)(b0 + lr) * D + k0 + lkc);
        Ak[lr][lkc] = c.x; Ak[lr][lkc + 1] = c.y; Ak[lr][lkc + 2] = c.z; Ak[lr][lkc + 3] = c.w;
        __syncthreads();
        #pragma unroll
        for (int kk = 0; kk < 16; ++kk) {
            float qa[4], kb[4];
            #pragma unroll
            for (int i = 0; i < 4; ++i) qa[i] = Aq[ty * 4 + i][kk];
            #pragma unroll
            for (int j = 0; j < 4; ++j) kb[j] = Ak[tx * 4 + j][kk];
            #pragma unroll
            for (int i = 0; i < 4; ++i)
                #pragma unroll
                for (int j = 0; j < 4; ++j) acc[i][j] += qa[i] * kb[j];
        }
        __syncthreads();
    }
    #pragma unroll
    for (int i = 0; i < 4; ++i)
        #pragma unroll
        for (int j = 0; j < 4; ++j)
            Mb[(size_t)(a0 + ty * 4 + i) * D + b0 + tx * 4 + j] = f2b(acc[i][j]);
}
__global__ __launch_bounds__(256) void kM(PP pp, u16* Mbuf, const int* flag) {
    __shared__ float Aq[64][17], Ak[64][17];
    int p = blockIdx.z;
    u16* Mb = Mbuf + (size_t)p * D * D;
    if (flag[0]) kM_body<1>(pp.W[2 * p], pp.W[2 * p + 1], Mb, Aq, Ak);
    else         kM_body<0>(pp.W[2 * p], pp.W[2 * p + 1], Mb, Aq, Ak);
}

// ---------------- kBias: z0 = Wk@bq, w1 = Wq@bk, c0 = bq·bk ----------------
template<int F32> __device__ void kBias_body(const void* Wq, const void* Wk,
        const void* bq, const void* bk, float* z0, float* w1, float* c0,
        float* bqs, float* bks, float* red, int p) {
    int tid = threadIdx.x;
    for (int i = tid; i < D; i += 256) { bqs[i] = ld1<F32>(bq, i); bks[i] = ld1<F32>(bk, i); }
    __syncthreads();
    for (int d = tid; d < D; d += 256) {
        float s1 = 0.f, s2 = 0.f;
        for (int j = 0; j < D; ++j) {
            s1 += ld1<F32>(Wk, (size_t)d * D + j) * bqs[j];
            s2 += ld1<F32>(Wq, (size_t)d * D + j) * bks[j];
        }
        z0[p * D + d] = s1; w1[p * D + d] = s2;
    }
    float pc = 0.f;
    for (int j = tid; j < D; j += 256) pc += bqs[j] * bks[j];
    red[tid] = pc; __syncthreads();
    for (int s = 128; s > 0; s >>= 1) { if (tid < s) red[tid] += red[tid + s]; __syncthreads(); }
    if (tid == 0) c0[p] = red[0];
}
__global__ __launch_bounds__(256) void kBias(PP pp, float* z0, float* w1, float* c0,
        const int* flag) {
    __shared__ float bqs[D], bks[D], red[256];
    int p = blockIdx.x;
    if (flag[0]) kBias_body<1>(pp.W[2 * p], pp.W[2 * p + 1], pp.b[2 * p], pp.b[2 * p + 1], z0, w1, c0, bqs, bks, red, p);
    else         kBias_body<0>(pp.W[2 * p], pp.W[2 * p + 1], pp.b[2 * p], pp.b[2 * p + 1], z0, w1, c0, bqs, bks, red, p);
}

// ---------------- kT: t[p][b][l] = x_l·w1_p + c0_p  (l < 512) ----------------
template<int F32> __device__ void kT_body(const void* x, const float* w1,
        const float* c0, float* tbuf, float* w1s) {
    int tid = threadIdx.x;
    int b = blockIdx.y, p = blockIdx.z;
    for (int i = tid; i < D; i += 256) w1s[i] = w1[p * D + i];
    __syncthreads();
    int row = blockIdx.x * 64 + (tid >> 2);   // [0,512)
    int sub = tid & 3;
    float acc = 0.f;
    for (int i = 0; i < 48; ++i) {
        int k = i * 16 + sub * 4;
        float4 xv = ld4<F32>(x, ((size_t)b * L + row) * D + k);
        acc += xv.x * w1s[k] + xv.y * w1s[k + 1] + xv.z * w1s[k + 2] + xv.w * w1s[k + 3];
    }
    acc += __shfl_xor(acc, 1);
    acc += __shfl_xor(acc, 2);
    if (sub == 0) tbuf[((size_t)p * NB + b) * 512 + row] = acc + c0[p];
}
__global__ __launch_bounds__(256) void kT(const void* x, const float* w1,
        const float* c0, float* tbuf, const int* flag) {
    __shared__ float w1s[D];
    if (flag[0]) kT_body<1>(x, w1, c0, tbuf, w1s);
    else         kT_body<0>(x, w1, c0, tbuf, w1s);
}

// ---------------- kZ: Z = x@M + z0  (rows < sep, bf16 out) ----------------
template<int F32> __device__ void kZ_body(const void* x, const u16* Mb,
        const float* z0p, u16* Zout, int b, int r0, int j0,
        float (*Xs)[17], float (*Ms)[65]) {
    int tid = threadIdx.x, tx = tid & 15, ty = tid >> 4;
    int lr = tid >> 2, lkc = (tid & 3) << 2;
    int wr = tid >> 4, wjc = (tid & 15) << 2;
    float acc[4][4];
    #pragma unroll
    for (int i = 0; i < 4; ++i)
        #pragma unroll
        for (int j = 0; j < 4; ++j) acc[i][j] = 0.f;
    for (int k0 = 0; k0 < D; k0 += 16) {
        float4 xv = ld4<F32>(x, ((size_t)b * L + r0 + lr) * D + k0 + lkc);
        Xs[lr][lkc] = xv.x; Xs[lr][lkc + 1] = xv.y; Xs[lr][lkc + 2] = xv.z; Xs[lr][lkc + 3] = xv.w;
        ushort4 mv = *(const ushort4*)(Mb + (size_t)(k0 + wr) * D + j0 + wjc);
        Ms[wr][wjc] = b2f(mv.x); Ms[wr][wjc + 1] = b2f(mv.y);
        Ms[wr][wjc + 2] = b2f(mv.z); Ms[wr][wjc + 3] = b2f(mv.w);
        __syncthreads();
        #pragma unroll
        for (int kk = 0; kk < 16; ++kk) {
            float xa[4], wb[4];
            #pragma unroll
            for (int i = 0; i < 4; ++i) xa[i] = Xs[ty * 4 + i][kk];
            #pragma unroll
            for (int j = 0; j < 4; ++j) wb[j] = Ms[kk][tx * 4 + j];
            #pragma unroll
            for (int i = 0; i < 4; ++i)
                #pragma unroll
                for (int j = 0; j < 4; ++j) acc[i][j] += xa[i] * wb[j];
        }
        __syncthreads();
    }
    #pragma unroll
    for (int i = 0; i < 4; ++i) {
        int row = r0 + ty * 4 + i;
        #pragma unroll
        for (int j = 0; j < 4; ++j) {
            int col = j0 + tx * 4 + j;
            Zout[(size_t)row * D + col] = f2b(acc[i][j] + z0p[col]);
        }
    }
}
__global__ __launch_bounds__(256) void kZ(const void* x, const u16* Mbuf,
        const float* z0, u16* Zbuf, const int* sepArr, const int* flag) {
    __shared__ float Xs[64][17], Ms[16][65];
    int bz = blockIdx.z;
    int p = bz / NB, b = bz % NB;
    int sep = sepArr[b];
    int r0 = blockIdx.y * 64;
    if (r0 >= sep) return;
    int j0 = blockIdx.x * 64;
    const u16* Mb = Mbuf + (size_t)p * D * D;
    u16* Zout = Zbuf + ((size_t)p * NB + b) * 512 * D;
    if (flag[0]) kZ_body<1>(x, Mb, z0 + p * D, Zout, b, r0, j0, Xs, Ms);
    else         kZ_body<0>(x, Mb, z0 + p * D, Zout, b, r0, j0, Xs, Ms);
}

// ---------------- kS_sup: S = (Zs·x^T + t) * scale  (bf16 out) ----------------
template<int F32> __device__ void kSsup_body(const u16* Zp, const void* x,
        const float* tp, u16* Sout, int b, int l0, int m0,
        float (*Zs)[17], float (*Xs)[17]) {
    int tid = threadIdx.x, tx = tid & 15, ty = tid >> 4;
    int lr = tid >> 2, lkc = (tid & 3) << 2;
    float acc[4][4];
    #pragma unroll
    for (int i = 0; i < 4; ++i)
        #pragma unroll
        for (int j = 0; j < 4; ++j) acc[i][j] = 0.f;
    for (int k0 = 0; k0 < D; k0 += 16) {
        ushort4 zv = *(const ushort4*)(Zp + (size_t)(l0 + lr) * D + k0 + lkc);
        Zs[lr][lkc] = b2f(zv.x); Zs[lr][lkc + 1] = b2f(zv.y);
        Zs[lr][lkc + 2] = b2f(zv.z); Zs[lr][lkc + 3] = b2f(zv.w);
        float4 xv = ld4<F32>(x, ((size_t)b * L + m0 + lr) * D + k0 + lkc);
        Xs[lr][lkc] = xv.x; Xs[lr][lkc + 1] = xv.y; Xs[lr][lkc + 2] = xv.z; Xs[lr][lkc + 3] = xv.w;
        __syncthreads();
        #pragma unroll
        for (int kk = 0; kk < 16; ++kk) {
            float qa[4], kb[4];
            #pragma unroll
            for (int i = 0; i < 4; ++i) qa[i] = Zs[ty * 4 + i][kk];
            #pragma unroll
            for (int j = 0; j < 4; ++j) kb[j] = Xs[tx * 4 + j][kk];
            #pragma unroll
            for (int i = 0; i < 4; ++i)
                #pragma unroll
                for (int j = 0; j < 4; ++j) acc[i][j] += qa[i] * kb[j];
        }
        __syncthreads();
    }
    #pragma unroll
    for (int i = 0; i < 4; ++i) {
        int row = l0 + ty * 4 + i;
        float t = tp[row];
        #pragma unroll
        for (int j = 0; j < 4; ++j)
            Sout[(size_t)row * L + m0 + tx * 4 + j] = f2b((acc[i][j] + t) * SCALE);
    }
}
__global__ __launch_bounds__(256) void kS_sup(const u16* Zbuf, const void* x,
        const float* tbuf, const int* sepArr, u16* ssup, const int* flag) {
    __shared__ float Zs[64][17], Xs[64][17];
    int b = blockIdx.z;
    int sep = sepArr[b];
    int l0 = blockIdx.y * 64;
    if (l0 >= sep) return;
    int m0 = blockIdx.x * 64;
    if (m0 + 63 <= sep) return;
    const u16* Zp = Zbuf + ((size_t)0 * NB + b) * 512 * D;
    const float* tp = tbuf + ((size_t)0 * NB + b) * 512;
    u16* Sout = ssup + (size_t)b * 512 * L;
    if (flag[0]) kSsup_body<1>(Zp, x, tp, Sout, b, l0, m0, Zs, Xs);
    else         kSsup_body<0>(Zp, x, tp, Sout, b, l0, m0, Zs, Xs);
}

// ---------------- kS_comb: S = (Zr·x+tr)*scale + tanh((Zc·x+tc)*scale) ----------------
template<int F32> __device__ void kScmb_body(const u16* Zr, const u16* Zc, const void* x,
        const float* tr, const float* tc, u16* Sout, int b, int l0, int m0,
        float (*Zrs)[17], float (*Zcs)[17], float (*Xs)[17]) {
    int tid = threadIdx.x, tx = tid & 15, ty = tid >> 4;
    int lr = tid >> 2, lkc = (tid & 3) << 2;
    float ar[4][4], ac[4][4];
    #pragma unroll
    for (int i = 0; i < 4; ++i)
        #pragma unroll
        for (int j = 0; j < 4; ++j) { ar[i][j] = 0.f; ac[i][j] = 0.f; }
    for (int k0 = 0; k0 < D; k0 += 16) {
        ushort4 v;
        v = *(const ushort4*)(Zr + (size_t)(l0 + lr) * D + k0 + lkc);
        Zrs[lr][lkc] = b2f(v.x); Zrs[lr][lkc + 1] = b2f(v.y);
        Zrs[lr][lkc + 2] = b2f(v.z); Zrs[lr][lkc + 3] = b2f(v.w);
        v = *(const ushort4*)(Zc + (size_t)(l0 + lr) * D + k0 + lkc);
        Zcs[lr][lkc] = b2f(v.x); Zcs[lr][lkc + 1] = b2f(v.y);
        Zcs[lr][lkc + 2] = b2f(v.z); Zcs[lr][lkc + 3] = b2f(v.w);
        float4 xv = ld4<F32>(x, ((size_t)b * L + m0 + lr) * D + k0 + lkc);
        Xs[lr][lkc] = xv.x; Xs[lr][lkc + 1] = xv.y; Xs[lr][lkc + 2] = xv.z; Xs[lr][lkc + 3] = xv.w;
        __syncthreads();
        #pragma unroll
        for (int kk = 0; kk < 16; ++kk) {
            float ra[4], ca[4], xb[4];
            #pragma unroll
            for (int i = 0; i < 4; ++i) { ra[i] = Zrs[ty * 4 + i][kk]; ca[i] = Zcs[ty * 4 + i][kk]; }
            #pragma unroll
            for (int j = 0; j < 4; ++j) xb[j] = Xs[tx * 4 + j][kk];
            #pragma unroll
            for (int i = 0; i < 4; ++i)
                #pragma unroll
                for (int j = 0; j < 4; ++j) {
                    ar[i][j] += ra[i] * xb[j];
                    ac[i][j] += ca[i] * xb[j];
                }
        }
        __syncthreads();
    }
    #pragma unroll
    for (int i = 0; i < 4; ++i) {
        int row = l0 + ty * 4 + i;
        float trv = tr[row], tcv = tc[row];
        #pragma unroll
        for (int j = 0; j < 4; ++j) {
            float vv = (ar[i][j] + trv) * SCALE + tanhf((ac[i][j] + tcv) * SCALE);
            Sout[(size_t)row * L + m0 + tx * 4 + j] = f2b(vv);
        }
    }
}
__global__ __launch_bounds__(256) void kS_comb(const u16* Zbuf, const void* x,
        const float* tbuf, const int* sepArr, u16* scmb, const int* flag) {
    __shared__ float Zrs[64][17], Zcs[64][17], Xs[64][17];
    int b = blockIdx.z;
    int sep = sepArr[b];
    int l0 = blockIdx.y * 64;
    if (l0 >= sep) return;
    int m0 = blockIdx.x * 64;
    if (m0 + 63 <= sep) return;
    const u16* Zr = Zbuf + ((size_t)2 * NB + b) * 512 * D;  // rep
    const u16* Zc = Zbuf + ((size_t)1 * NB + b) * 512 * D;  // con
    const float* tr = tbuf + ((size_t)2 * NB + b) * 512;
    const float* tc = tbuf + ((size_t)1 * NB + b) * 512;
    u16* Sout = scmb + (size_t)b * 512 * L;
    if (flag[0]) kScmb_body<1>(Zr, Zc, x, tr, tc, Sout, b, l0, m0, Zrs, Zcs, Xs);
    else         kScmb_body<0>(Zr, Zc, x, tr, tc, Sout, b, l0, m0, Zrs, Zcs, Xs);
}

// ---------------- K2b: per-row masked softmax + column-weight accumulation ----------------
__global__ __launch_bounds__(256) void k2b(const u16* __restrict__ ssup,
        const u16* __restrict__ scmb, const int* __restrict__ ids,
        const int* __restrict__ padp, const int* __restrict__ sepArr,
        const float* __restrict__ gate, float* __restrict__ csup,
        float* __restrict__ crep, const int* __restrict__ flag) {
    int b = blockIdx.y, l = blockIdx.x;
    int sep = sepArr[b];
    if (l >= sep) return;
    float g = gate[b * L + l];
    if (g == 0.f) return;
    int is64 = flag[1];
    int pad = padp[0];
    int tid = threadIdx.x;
    __shared__ float red[256];
    float s0[4], s1[4];
    const u16* rs = ssup + ((size_t)b * 512 + l) * L;
    const u16* rc = scmb + ((size_t)b * 512 + l) * L;
    float mx0 = -3.4e38f, mx1 = -3.4e38f;
    for (int u = 0; u < 4; ++u) {
        int m = tid + u * 256;
        bool ok = (m > sep) && (ldid(ids, (size_t)b * L + m, is64) != pad);
        s0[u] = ok ? b2f(rs[m]) : NEGV;
        s1[u] = ok ? b2f(rc[m]) : NEGV;
        mx0 = fmaxf(mx0, s0[u]); mx1 = fmaxf(mx1, s1[u]);
    }
    red[tid] = mx0; __syncthreads();
    for (int s = 128; s > 0; s >>= 1) { if (tid < s) red[tid] = fmaxf(red[tid], red[tid + s]); __syncthreads(); }
    mx0 = red[0]; __syncthreads();
    red[tid] = mx1; __syncthreads();
    for (int s = 128; s > 0; s >>= 1) { if (tid < s) red[tid] = fmaxf(red[tid], red[tid + s]); __syncthreads(); }
    mx1 = red[0]; __syncthreads();
    float e0s = 0.f, e1s = 0.f;
    for (int u = 0; u < 4; ++u) {
        s0[u] = expf(s0[u] - mx0); e0s += s0[u];
        s1[u] = expf(s1[u] - mx1); e1s += s1[u];
    }
    red[tid] = e0s; __syncthreads();
    for (int s = 128; s > 0; s >>= 1) { if (tid < s) red[tid] += red[tid + s]; __syncthreads(); }
    float d0 = fmaxf(red[0], 1e-30f); __syncthreads();
    red[tid] = e1s; __syncthreads();
    for (int s = 128; s > 0; s >>= 1) { if (tid < s) red[tid] += red[tid + s]; __syncthreads(); }
    float d1 = fmaxf(red[0], 1e-30f);
    float i0 = g / d0, i1 = g / d1;
    for (int u = 0; u < 4; ++u) {
        int m = tid + u * 256;
        float p0 = s0[u] * i0;
        float p1 = s1[u] * i1;
        if (p0 != 0.f) atomicAdd(&csup[b * L + m], p0);
        if (p1 != 0.f) atomicAdd(&crep[b * L + m], p1);
    }
}

// ---------------- K3: af/w_rep/w_sup weighted sums over x ----------------
template<int F32> __device__ void k3_body(const void* x, const float* gate,
        const float* csup, const float* crep, float* af, float* wrep, float* wsup) {
    int b = blockIdx.y, c = blockIdx.x;
    int tid = threadIdx.x;
    float a0 = 0.f, a1 = 0.f, a2 = 0.f;
    float r0 = 0.f, r1 = 0.f, r2 = 0.f;
    float q0 = 0.f, q1 = 0.f, q2 = 0.f;
    for (int mm = 0; mm < 128; ++mm) {
        int m = c * 128 + mm;
        float wg = gate[b * L + m], wr = crep[b * L + m], wq = csup[b * L + m];
        if (wg == 0.f && wr == 0.f && wq == 0.f) continue;
        size_t base = ((size_t)b * L + m) * D;
        float x0 = ld1<F32>(x, base + tid);
        float x1 = ld1<F32>(x, base + tid + 256);
        float x2 = ld1<F32>(x, base + tid + 512);
        a0 += wg * x0; a1 += wg * x1; a2 += wg * x2;
        r0 += wr * x0; r1 += wr * x1; r2 += wr * x2;
        q0 += wq * x0; q1 += wq * x1; q2 += wq * x2;
    }
    atomicAdd(&af[b * D + tid], a0); atomicAdd(&af[b * D + tid + 256], a1); atomicAdd(&af[b * D + tid + 512], a2);
    atomicAdd(&wrep[b * D + tid], r0); atomicAdd(&wrep[b * D + tid + 256], r1); atomicAdd(&wrep[b * D + tid + 512], r2);
    atomicAdd(&wsup[b * D + tid], q0); atomicAdd(&wsup[b * D + tid + 256], q1); atomicAdd(&wsup[b * D + tid + 512], q2);
}
__global__ __launch_bounds__(256) void k3(const void* x, const float* gate,
        const float* csup, const float* crep, float* af, float* wrep, float* wsup,
        const int* flag) {
    if (flag[0]) k3_body<1>(x, gate, csup, crep, af, wrep, wsup);
    else         k3_body<0>(x, gate, csup, crep, af, wrep, wsup);
}

// ---------------- K4a: h = relu([af,wrep,wsup] @ Wf1 + bf1) ----------------
template<int F32> __device__ void k4a_body(const float* af, const float* wrep,
        const float* wsup, const void* Wf1, const void* bf1, float* h, float* fin) {
    int b = blockIdx.y;
    int j = blockIdx.x * 256 + threadIdx.x;
    int tid = threadIdx.x;
    for (int i = tid; i < D; i += 256) {
        fin[i] = af[b * D + i];
        fin[D + i] = wrep[b * D + i];
        fin[2 * D + i] = wsup[b * D + i];
    }
    __syncthreads();
    float acc = ld1<F32>(bf1, j);
    for (int i = 0; i < 3 * D; ++i) acc += fin[i] * ld1<F32>(Wf1, (size_t)i * D + j);
    h[b * D + j] = fmaxf(acc, 0.f);
}
__global__ __launch_bounds__(256) void k4a(const float* af, const float* wrep,
        const float* wsup, const void* Wf1, const void* bf1, float* h, const int* flag) {
    __shared__ float fin[3 * D];
    if (flag[0]) k4a_body<1>(af, wrep, wsup, Wf1, bf1, h, fin);
    else         k4a_body<0>(af, wrep, wsup, Wf1, bf1, h, fin);
}

// ---------------- K4b: out = LN(h @ Wf2 + bf2) * gamma + beta ----------------
template<int F32> __device__ void k4b_body(const float* h, const void* Wf2,
        const void* bf2, const void* gamma, const void* beta, void* out,
        float* hs, float* red) {
    int b = blockIdx.x, tid = threadIdx.x;
    for (int i = tid; i < D; i += 256) hs[i] = h[b * D + i];
    __syncthreads();
    float o[3];
    #pragma unroll
    for (int u = 0; u < 3; ++u) {
        int i = tid + u * 256;
        float acc = ld1<F32>(bf2, i);
        for (int j = 0; j < D; ++j) acc += hs[j] * ld1<F32>(Wf2, (size_t)j * D + i);
        o[u] = acc;
    }
    red[tid] = o[0] + o[1] + o[2]; __syncthreads();
    for (int s = 128; s > 0; s >>= 1) { if (tid < s) red[tid] += red[tid + s]; __syncthreads(); }
    float mu = red[0] / (float)D; __syncthreads();
    float vs = 0.f;
    #pragma unroll
    for (int u = 0; u < 3; ++u) vs += (o[u] - mu) * (o[u] - mu);
    red[tid] = vs; __syncthreads();
    for (int s = 128; s > 0; s >>= 1) { if (tid < s) red[tid] += red[tid + s]; __syncthreads(); }
    float var = red[0] / (float)D;
    float rstd = 1.0f / sqrtf(var + 1e-5f);
    #pragma unroll
    for (int u = 0; u < 3; ++u) {
        int i = tid + u * 256;
        float v = (o[u] - mu) * rstd * ld1<F32>(gamma, i) + ld1<F32>(beta, i);
        if (F32) ((float*)out)[b * D + i] = v;
        else     ((u16*)out)[b * D + i] = f2b(v);
    }
}
__global__ __launch_bounds__(256) void k4b(const float* h, const void* Wf2,
        const void* bf2, const void* gamma, const void* beta, void* out,
        const int* flag) {
    __shared__ float hs[D], red[256];
    if (flag[0]) k4b_body<1>(h, Wf2, bf2, gamma, beta, out, hs, red);
    else         k4b_body<0>(h, Wf2, bf2, gamma, beta, out, hs, red);
}

extern "C" void kernel_launch(void* const* d_in, const int* in_sizes, int n_in,
                              void* d_out, int out_size, void* d_ws, size_t ws_size,
                              hipStream_t stream) {
    const void* x    = d_in[0];
    const int* ids   = (const int*)d_in[1];
    const int* padp  = (const int*)d_in[2];
    const void* Wa   = d_in[3];
    const void* ba   = d_in[4];
    PP pp;
    pp.W[0] = d_in[5];  pp.b[0] = d_in[6];    // qs
    pp.W[1] = d_in[7];  pp.b[1] = d_in[8];    // ks
    pp.W[2] = d_in[9];  pp.b[2] = d_in[10];   // qc
    pp.W[3] = d_in[11]; pp.b[3] = d_in[12];   // kc
    pp.W[4] = d_in[13]; pp.b[4] = d_in[14];   // qr
    pp.W[5] = d_in[15]; pp.b[5] = d_in[16];   // kr
    const void* Wf1 = d_in[17]; const void* bf1 = d_in[18];
    const void* Wf2 = d_in[19]; const void* bf2 = d_in[20];
    const void* gamma = d_in[21]; const void* beta = d_in[22];

    char* ws = (char*)d_ws;
    int*   flag   = (int*)(ws + WS_FLAG);
    int*   sepArr = (int*)(ws + WS_SEP);
    float* c0   = (float*)(ws + WS_C0);
    float* z0   = (float*)(ws + WS_Z0);
    float* w1   = (float*)(ws + WS_W1);
    float* gate = (float*)(ws + WS_GATE);
    float* csup = (float*)(ws + WS_CSUP);
    float* crep = (float*)(ws + WS_CREP);
    float* af   = (float*)(ws + WS_AF);
    float* wrep = (float*)(ws + WS_WREP);
    float* wsup = (float*)(ws + WS_WSUP);
    float* h    = (float*)(ws + WS_H);
    float* alog = (float*)(ws + WS_ALOG);
    float* tbuf = (float*)(ws + WS_T);
    u16* Mbuf = (u16*)(ws + WS_M);
    u16* Zbuf = (u16*)(ws + WS_Z);
    u16* ssup = (u16*)(ws + WS_SSUP);
    u16* scmb = (u16*)(ws + WS_SCMB);

    kdetect<<<dim3(1), dim3(128), 0, stream>>>(x, ids, flag);
    k0a<<<dim3(NB * L / 64), dim3(256), 0, stream>>>(x, Wa, ba, alog, flag);
    k0b<<<dim3(NB), dim3(256), 0, stream>>>(ids, padp, alog, gate, sepArr,
                                            csup, crep, af, wrep, wsup, flag);
    kM<<<dim3(12, 12, 3), dim3(256), 0, stream>>>(pp, Mbuf, flag);
    kBias<<<dim3(3), dim3(256), 0, stream>>>(pp, z0, w1, c0, flag);
    kT<<<dim3(8, NB, 3), dim3(256), 0, stream>>>(x, w1, c0, tbuf, flag);
    kZ<<<dim3(12, 8, NB * 3), dim3(256), 0, stream>>>(x, Mbuf, z0, Zbuf, sepArr, flag);
    kS_sup<<<dim3(16, 8, NB), dim3(256), 0, stream>>>(Zbuf, x, tbuf, sepArr, ssup, flag);
    kS_comb<<<dim3(16, 8, NB), dim3(256), 0, stream>>>(Zbuf, x, tbuf, sepArr, scmb, flag);
    k2b<<<dim3(512, NB), dim3(256), 0, stream>>>(ssup, scmb, ids, padp, sepArr,
                                                 gate, csup, crep, flag);
    k3<<<dim3(8, NB), dim3(256), 0, stream>>>(x, gate, csup, crep, af, wrep, wsup, flag);
    k4a<<<dim3(3, NB), dim3(256), 0, stream>>>(af, wrep, wsup, Wf1, bf1, h, flag);
    k4b<<<dim3(NB), dim3(256), 0, stream>>>(h, Wf2, bf2, gamma, beta, d_out, flag);
}

// Round 3
// 518.499 us; speedup vs baseline: 2.4827x; 2.4827x over previous
//
#include <hip/hip_runtime.h>
#include <math.h>

#define L 1024
#define NB 8
#define D 768
#define NEGV (-9.0e15f)
#define SCALE 0.036084391824351615f  // 1/sqrt(768)

typedef unsigned short u16;
typedef __attribute__((ext_vector_type(8))) short short8;
typedef __attribute__((ext_vector_type(4))) float float4v;
#define MFMA_BF16 __builtin_amdgcn_mfma_f32_16x16x32_bf16

__device__ __forceinline__ float b2f(u16 u) {
    union { unsigned int i; float f; } v; v.i = ((unsigned int)u) << 16; return v.f;
}
__device__ __forceinline__ u16 f2b(float f) {
    union { float fv; unsigned int i; } v; v.fv = f;
    unsigned int x = v.i;
    x += 0x7fffu + ((x >> 16) & 1u);   // RNE
    return (u16)(x >> 16);
}

template<int F32>
__device__ __forceinline__ float4 ld4(const void* p, size_t idx) {
    if (F32) return *(const float4*)((const float*)p + idx);
    ushort4 v = *(const ushort4*)((const u16*)p + idx);
    return make_float4(b2f(v.x), b2f(v.y), b2f(v.z), b2f(v.w));
}
template<int F32>
__device__ __forceinline__ float ld1(const void* p, size_t idx) {
    if (F32) return ((const float*)p)[idx];
    return b2f(((const u16*)p)[idx]);
}
__device__ __forceinline__ int ldid(const int* p, size_t idx, int is64) {
    return is64 ? p[idx * 2] : p[idx];
}

// ---------------- workspace layout (bytes) ----------------
#define WS_FLAG  ((size_t)0)
#define WS_SEP   ((size_t)64)
#define WS_C0    ((size_t)128)
#define WS_Z0    ((size_t)192)
#define WS_W1    ((size_t)9472)
#define WS_GATE  ((size_t)18752)
#define WS_CSUP  ((size_t)51520)
#define WS_CREP  ((size_t)84288)
#define WS_AF    ((size_t)117056)
#define WS_WREP  ((size_t)141632)
#define WS_WSUP  ((size_t)166208)
#define WS_H     ((size_t)190784)
#define WS_ALOG  ((size_t)215360)
#define WS_T     ((size_t)248128)     // 3*NB*512 f32 -> ends 297280
#define WS_XB    ((size_t)524288)     // NB*L*D bf16 = 12.58 MB -> 13107200
#define WS_Z     ((size_t)13107200)   // 3*NB*512*D bf16 = 18.87 MB -> 31981568
#define WS_SSUP  ((size_t)31981568)   // NB*512*L bf16 = 8.39 MB -> 40370176
#define WS_WB    WS_SSUP              // 6*D*D bf16 = 7.08 MB (dead before kS_sup writes)
#define WS_SCMB  ((size_t)40370176)   // NB*512*L bf16 -> 48758784 (~46.5 MB total)
#define WS_M     WS_SCMB              // 3*D*D bf16 = 3.54 MB (dead before kS_comb writes)

struct PP { const void* W[6]; const void* b[6]; };

// ---------------- detect dtypes ----------------
__global__ __launch_bounds__(128) void kdetect(const void* x, const void* ids, int* flag) {
    __shared__ int cnt[2];
    int tid = threadIdx.x;
    if (tid == 0) { cnt[0] = 0; cnt[1] = 0; }
    __syncthreads();
    if (tid < 64) {
        u16 u = ((const u16*)x)[tid * 2];
        int e = (u >> 7) & 0xFF;
        if (e >= 100 && e <= 140) atomicAdd(&cnt[0], 1);
    } else {
        int v = ((const int*)ids)[(tid - 64) * 2 + 1];
        if (v != 0) atomicAdd(&cnt[1], 1);
    }
    __syncthreads();
    if (tid == 0) {
        flag[0] = (cnt[0] < 32) ? 1 : 0;   // 1 => floats are f32
        flag[1] = (cnt[1] == 0) ? 1 : 0;   // 1 => ids are int64
    }
}

// ---------------- kconvx: x -> bf16 ----------------
__global__ __launch_bounds__(256) void kconvx(const void* x, u16* xb, const int* flag) {
    size_t base = ((size_t)blockIdx.x * 256 + threadIdx.x) * 8;
    if (flag[0]) {
        float4 a = *(const float4*)((const float*)x + base);
        float4 b = *(const float4*)((const float*)x + base + 4);
        uint4 o; u16* po = (u16*)&o;
        po[0] = f2b(a.x); po[1] = f2b(a.y); po[2] = f2b(a.z); po[3] = f2b(a.w);
        po[4] = f2b(b.x); po[5] = f2b(b.y); po[6] = f2b(b.z); po[7] = f2b(b.w);
        *(uint4*)(xb + base) = o;
    } else {
        *(uint4*)(xb + base) = *(const uint4*)((const u16*)x + base);
    }
}

// ---------------- kconvw: 6 weight matrices -> bf16 ----------------
__global__ __launch_bounds__(256) void kconvw(PP pp, u16* Wb, const int* flag) {
    int t = blockIdx.y;
    size_t base = ((size_t)blockIdx.x * 256 + threadIdx.x) * 8;
    u16* dst = Wb + (size_t)t * D * D;
    const void* src = pp.W[t];
    if (flag[0]) {
        float4 a = *(const float4*)((const float*)src + base);
        float4 b = *(const float4*)((const float*)src + base + 4);
        uint4 o; u16* po = (u16*)&o;
        po[0] = f2b(a.x); po[1] = f2b(a.y); po[2] = f2b(a.z); po[3] = f2b(a.w);
        po[4] = f2b(b.x); po[5] = f2b(b.y); po[6] = f2b(b.z); po[7] = f2b(b.w);
        *(uint4*)(dst + base) = o;
    } else {
        *(uint4*)(dst + base) = *(const uint4*)((const u16*)src + base);
    }
}

// ---------------- K0a: a_logits = x @ Wa + ba ----------------
template<int F32> __device__ void k0a_body(const void* x, const void* Wa,
        const void* ba, float* alog, float* was) {
    int tid = threadIdx.x;
    for (int i = tid; i < D; i += 256) was[i] = ld1<F32>(Wa, i);
    __syncthreads();
    int row = blockIdx.x * 64 + (tid >> 2);
    int sub = tid & 3;
    float acc = 0.f;
    for (int i = 0; i < 48; ++i) {
        int k = i * 16 + sub * 4;
        float4 xv = ld4<F32>(x, (size_t)row * D + k);
        acc += xv.x * was[k] + xv.y * was[k + 1] + xv.z * was[k + 2] + xv.w * was[k + 3];
    }
    acc += __shfl_xor(acc, 1);
    acc += __shfl_xor(acc, 2);
    if (sub == 0) alog[row] = acc + ld1<F32>(ba, 0);
}
__global__ __launch_bounds__(256) void k0a(const void* x, const void* Wa,
        const void* ba, float* alog, const int* flag) {
    __shared__ float was[D];
    if (flag[0]) k0a_body<1>(x, Wa, ba, alog, was);
    else         k0a_body<0>(x, Wa, ba, alog, was);
}

// ---------------- K0b: sep, gate softmax, zero accumulators ----------------
__global__ __launch_bounds__(256) void k0b(const int* __restrict__ ids,
        const int* __restrict__ padp, const float* __restrict__ alog,
        float* __restrict__ gate, int* __restrict__ sepArr,
        float* __restrict__ af, float* __restrict__ wrep, float* __restrict__ wsup,
        const int* __restrict__ flag) {
    __shared__ float red[256];
    __shared__ int sepSh;
    int is64 = flag[1];
    int b = blockIdx.x, tid = threadIdx.x;
    int pad = padp[0];
    int cnt = 0;
    for (int l = tid; l < L; l += 256) cnt += (ldid(ids, (size_t)b * L + l, is64) != pad) ? 1 : 0;
    red[tid] = (float)cnt; __syncthreads();
    for (int s = 128; s > 0; s >>= 1) { if (tid < s) red[tid] += red[tid + s]; __syncthreads(); }
    if (tid == 0) {
        int vl = (int)red[0];
        int sep = vl / 2; if (sep < 1) sep = 1; if (sep > L - 2) sep = L - 2;
        sepSh = sep; sepArr[b] = sep;
    }
    __syncthreads();
    int sep = sepSh;
    float lv[4]; int lidx[4];
    float mx = -3.4e38f;
    for (int u = 0; u < 4; ++u) {
        int l = tid + u * 256; lidx[u] = l;
        bool fm = (l < sep) && (ldid(ids, (size_t)b * L + l, is64) != pad);
        float v = fm ? alog[b * L + l] : NEGV;
        lv[u] = v; mx = fmaxf(mx, v);
    }
    red[tid] = mx; __syncthreads();
    for (int s = 128; s > 0; s >>= 1) { if (tid < s) red[tid] = fmaxf(red[tid], red[tid + s]); __syncthreads(); }
    mx = red[0]; __syncthreads();
    float se = 0.f;
    for (int u = 0; u < 4; ++u) { lv[u] = expf(lv[u] - mx); se += lv[u]; }
    red[tid] = se; __syncthreads();
    for (int s = 128; s > 0; s >>= 1) { if (tid < s) red[tid] += red[tid + s]; __syncthreads(); }
    float den = fmaxf(red[0], 1e-30f); __syncthreads();
    float gs = 0.f; float gv[4];
    for (int u = 0; u < 4; ++u) {
        int l = lidx[u];
        bool fm = (l < sep) && (ldid(ids, (size_t)b * L + l, is64) != pad);
        float p = lv[u] / den;
        gv[u] = fm ? p : 0.f;
        gs += gv[u];
    }
    red[tid] = gs; __syncthreads();
    for (int s = 128; s > 0; s >>= 1) { if (tid < s) red[tid] += red[tid + s]; __syncthreads(); }
    gs = red[0];
    float inv = 1.f / fmaxf(gs, 1e-8f);
    for (int u = 0; u < 4; ++u) gate[b * L + lidx[u]] = gv[u] * inv;
    for (int i = tid; i < D; i += 256) { af[b * D + i] = 0.f; wrep[b * D + i] = 0.f; wsup[b * D + i] = 0.f; }
}

// ---------------- kbias_row: z0 = Wk@bq (which=0), w1 = Wq@bk (which=1) ----------------
template<int F32> __device__ void kbias_body(const void* W, const void* vec,
        float* out, float* vs) {
    int tid = threadIdx.x;
    for (int i = tid; i < D; i += 256) vs[i] = ld1<F32>(vec, i);
    __syncthreads();
    int row = blockIdx.x * 64 + (tid >> 2);
    int sub = tid & 3;
    float acc = 0.f;
    for (int i = 0; i < 48; ++i) {
        int k = i * 16 + sub * 4;
        float4 wv = ld4<F32>(W, (size_t)row * D + k);
        acc += wv.x * vs[k] + wv.y * vs[k + 1] + wv.z * vs[k + 2] + wv.w * vs[k + 3];
    }
    acc += __shfl_xor(acc, 1);
    acc += __shfl_xor(acc, 2);
    if (sub == 0) out[row] = acc;
}
__global__ __launch_bounds__(256) void kbias_row(PP pp, float* z0, float* w1,
        const int* flag) {
    __shared__ float vs[D];
    int y = blockIdx.y;
    int p = y >> 1, which = y & 1;
    const void* W   = which ? pp.W[2 * p]     : pp.W[2 * p + 1];
    const void* vec = which ? pp.b[2 * p + 1] : pp.b[2 * p];
    float* out = (which ? w1 : z0) + p * D;
    if (flag[0]) kbias_body<1>(W, vec, out, vs);
    else         kbias_body<0>(W, vec, out, vs);
}

// ---------------- kc0: c0[p] = bq . bk ----------------
template<int F32> __device__ void kc0_body(const void* bq, const void* bk,
        float* c0, int p, float* red) {
    int tid = threadIdx.x;
    float s = 0.f;
    for (int i = tid; i < D; i += 256) s += ld1<F32>(bq, i) * ld1<F32>(bk, i);
    red[tid] = s; __syncthreads();
    for (int st = 128; st > 0; st >>= 1) { if (tid < st) red[tid] += red[tid + st]; __syncthreads(); }
    if (tid == 0) c0[p] = red[0];
}
__global__ __launch_bounds__(256) void kc0(PP pp, float* c0, const int* flag) {
    __shared__ float red[256];
    int p = blockIdx.x;
    if (flag[0]) kc0_body<1>(pp.b[2 * p], pp.b[2 * p + 1], c0, p, red);
    else         kc0_body<0>(pp.b[2 * p], pp.b[2 * p + 1], c0, p, red);
}

// ---------------- kT: t[p][b][l] = x_l . w1_p + c0_p  (l < 512) ----------------
template<int F32> __device__ void kT_body(const void* x, const float* w1,
        const float* c0, float* tbuf, float* w1s) {
    int tid = threadIdx.x;
    int b = blockIdx.y, p = blockIdx.z;
    for (int i = tid; i < D; i += 256) w1s[i] = w1[p * D + i];
    __syncthreads();
    int row = blockIdx.x * 64 + (tid >> 2);
    int sub = tid & 3;
    float acc = 0.f;
    for (int i = 0; i < 48; ++i) {
        int k = i * 16 + sub * 4;
        float4 xv = ld4<F32>(x, ((size_t)b * L + row) * D + k);
        acc += xv.x * w1s[k] + xv.y * w1s[k + 1] + xv.z * w1s[k + 2] + xv.w * w1s[k + 3];
    }
    acc += __shfl_xor(acc, 1);
    acc += __shfl_xor(acc, 2);
    if (sub == 0) tbuf[((size_t)p * NB + b) * 512 + row] = acc + c0[p];
}
__global__ __launch_bounds__(256) void kT(const void* x, const float* w1,
        const float* c0, float* tbuf, const int* flag) {
    __shared__ float w1s[D];
    if (flag[0]) kT_body<1>(x, w1, c0, tbuf, w1s);
    else         kT_body<0>(x, w1, c0, tbuf, w1s);
}

// ================= MFMA GEMM (A . B^T), BM=BN=128, BK=32 =================
__device__ __forceinline__ void stage128(const u16* __restrict__ G, size_t ld,
        int r0, int k0, u16* S, int tid) {
    int rowa = tid >> 2, koa = (tid & 3) << 3;
    *(uint4*)&S[rowa * 32 + koa] = *(const uint4*)&G[(size_t)(r0 + rowa) * ld + k0 + koa];
    *(uint4*)&S[(rowa + 64) * 32 + koa] = *(const uint4*)&G[(size_t)(r0 + rowa + 64) * ld + k0 + koa];
}

__device__ __forceinline__ void gemm_core128(const u16* __restrict__ A, size_t lda, int r0,
        const u16* __restrict__ B, size_t ldb, int c0, int K,
        u16* As, u16* Bs, float4v acc[4][4]) {
    int tid = threadIdx.x;
    int lane = tid & 63, wave = tid >> 6;
    int wm = (wave >> 1) << 6, wn = (wave & 1) << 6;
    int quad = lane >> 4, lrow = lane & 15;
    #pragma unroll
    for (int i = 0; i < 4; ++i)
        #pragma unroll
        for (int j = 0; j < 4; ++j) acc[i][j] = (float4v){0.f, 0.f, 0.f, 0.f};
    for (int k0 = 0; k0 < K; k0 += 32) {
        __syncthreads();
        stage128(A, lda, r0, k0, As, tid);
        stage128(B, ldb, c0, k0, Bs, tid);
        __syncthreads();
        short8 af[4], bf[4];
        #pragma unroll
        for (int i = 0; i < 4; ++i) af[i] = *(const short8*)&As[(wm + i * 16 + lrow) * 32 + quad * 8];
        #pragma unroll
        for (int j = 0; j < 4; ++j) bf[j] = *(const short8*)&Bs[(wn + j * 16 + lrow) * 32 + quad * 8];
        #pragma unroll
        for (int i = 0; i < 4; ++i)
            #pragma unroll
            for (int j = 0; j < 4; ++j)
                acc[i][j] = MFMA_BF16(af[i], bf[j], acc[i][j], 0, 0, 0);
    }
}

// kM: Mt[j][k'] = sum_c Wk[j][c] Wq[k'][c]   (Mt = M^T, row-major [768][768])
__global__ __launch_bounds__(256) void kM_mfma(const u16* __restrict__ Wb, u16* __restrict__ Mt) {
    __shared__ __align__(16) u16 As[128 * 32];
    __shared__ __align__(16) u16 Bs[128 * 32];
    int p = blockIdx.z;
    int r0 = blockIdx.y * 128, c0 = blockIdx.x * 128;
    float4v acc[4][4];
    gemm_core128(Wb + (size_t)(2 * p + 1) * D * D, D, r0,
                 Wb + (size_t)(2 * p) * D * D, D, c0, D, As, Bs, acc);
    int lane = threadIdx.x & 63, wave = threadIdx.x >> 6;
    int wm = (wave >> 1) << 6, wn = (wave & 1) << 6;
    int quad = lane >> 4, lrow = lane & 15;
    u16* out = Mt + (size_t)p * D * D;
    #pragma unroll
    for (int i = 0; i < 4; ++i)
        #pragma unroll
        for (int j = 0; j < 4; ++j) {
            int brow = r0 + wm + i * 16 + quad * 4;
            int col = c0 + wn + j * 16 + lrow;
            #pragma unroll
            for (int r = 0; r < 4; ++r)
                out[(size_t)(brow + r) * D + col] = f2b(acc[i][j][r]);
        }
}

// kZ: Z[l][j] = sum_k xb[l][k] Mt[j][k] + z0[j]
__global__ __launch_bounds__(256) void kZ_mfma(const u16* __restrict__ xb,
        const u16* __restrict__ Mt, const float* __restrict__ z0,
        u16* __restrict__ Zbuf, const int* __restrict__ sepArr) {
    __shared__ __align__(16) u16 As[128 * 32];
    __shared__ __align__(16) u16 Bs[128 * 32];
    int z = blockIdx.z;
    int p = z >> 3, b = z & 7;
    int sep = sepArr[b];
    int r0 = blockIdx.y * 128;
    if (r0 >= sep) return;
    int c0 = blockIdx.x * 128;
    float4v acc[4][4];
    gemm_core128(xb + (size_t)b * L * D, D, r0,
                 Mt + (size_t)p * D * D, D, c0, D, As, Bs, acc);
    int lane = threadIdx.x & 63, wave = threadIdx.x >> 6;
    int wm = (wave >> 1) << 6, wn = (wave & 1) << 6;
    int quad = lane >> 4, lrow = lane & 15;
    const float* z0p = z0 + p * D;
    u16* out = Zbuf + ((size_t)p * NB + b) * 512 * D;
    #pragma unroll
    for (int i = 0; i < 4; ++i)
        #pragma unroll
        for (int j = 0; j < 4; ++j) {
            int brow = r0 + wm + i * 16 + quad * 4;
            int col = c0 + wn + j * 16 + lrow;
            float zb = z0p[col];
            #pragma unroll
            for (int r = 0; r < 4; ++r)
                out[(size_t)(brow + r) * D + col] = f2b(acc[i][j][r] + zb);
        }
}

// kS_sup: S[l][m] = (sum_j Z0[l][j] xb[m][j] + t[l]) * SCALE
__global__ __launch_bounds__(256) void kSsup_mfma(const u16* __restrict__ Zbuf,
        const u16* __restrict__ xb, const float* __restrict__ tbuf,
        const int* __restrict__ sepArr, u16* __restrict__ ssup) {
    __shared__ __align__(16) u16 As[128 * 32];
    __shared__ __align__(16) u16 Bs[128 * 32];
    int b = blockIdx.z;
    int sep = sepArr[b];
    int l0 = blockIdx.y * 128;
    if (l0 >= sep) return;
    int m0 = blockIdx.x * 128;
    if (m0 + 127 <= sep) return;
    float4v acc[4][4];
    gemm_core128(Zbuf + (size_t)b * 512 * D, D, l0,
                 xb + (size_t)b * L * D, D, m0, D, As, Bs, acc);
    int lane = threadIdx.x & 63, wave = threadIdx.x >> 6;
    int wm = (wave >> 1) << 6, wn = (wave & 1) << 6;
    int quad = lane >> 4, lrow = lane & 15;
    const float* tp = tbuf + (size_t)b * 512;   // p=0
    u16* out = ssup + (size_t)b * 512 * L;
    #pragma unroll
    for (int i = 0; i < 4; ++i)
        #pragma unroll
        for (int j = 0; j < 4; ++j) {
            int brow = l0 + wm + i * 16 + quad * 4;
            int col = m0 + wn + j * 16 + lrow;
            #pragma unroll
            for (int r = 0; r < 4; ++r)
                out[(size_t)(brow + r) * L + col] = f2b((acc[i][j][r] + tp[brow + r]) * SCALE);
        }
}

// kS_comb: S[l][m] = (Zr.x + tr)*SCALE + tanh((Zc.x + tc)*SCALE), BM=64
__global__ __launch_bounds__(256) void kScmb_mfma(const u16* __restrict__ Zbuf,
        const u16* __restrict__ xb, const float* __restrict__ tbuf,
        const int* __restrict__ sepArr, u16* __restrict__ scmb) {
    __shared__ __align__(16) u16 Ar[64 * 32];
    __shared__ __align__(16) u16 Ac[64 * 32];
    __shared__ __align__(16) u16 Bs[128 * 32];
    int b = blockIdx.z;
    int sep = sepArr[b];
    int l0 = blockIdx.y * 64;
    if (l0 >= sep) return;
    int m0 = blockIdx.x * 128;
    if (m0 + 127 <= sep) return;
    const u16* Zr = Zbuf + ((size_t)2 * NB + b) * 512 * D;
    const u16* Zc = Zbuf + ((size_t)1 * NB + b) * 512 * D;
    const u16* X = xb + (size_t)b * L * D;
    int tid = threadIdx.x, lane = tid & 63, wave = tid >> 6;
    int wm = (wave >> 1) << 5, wn = (wave & 1) << 6;
    int quad = lane >> 4, lrow = lane & 15;
    float4v ar_[2][4], ac_[2][4];
    #pragma unroll
    for (int i = 0; i < 2; ++i)
        #pragma unroll
        for (int j = 0; j < 4; ++j) { ar_[i][j] = (float4v){0.f,0.f,0.f,0.f}; ac_[i][j] = (float4v){0.f,0.f,0.f,0.f}; }
    for (int k0 = 0; k0 < D; k0 += 32) {
        __syncthreads();
        {
            int row = tid >> 2, ko = (tid & 3) << 3;
            *(uint4*)&Ar[row * 32 + ko] = *(const uint4*)&Zr[(size_t)(l0 + row) * D + k0 + ko];
            *(uint4*)&Ac[row * 32 + ko] = *(const uint4*)&Zc[(size_t)(l0 + row) * D + k0 + ko];
        }
        stage128(X, D, m0, k0, Bs, tid);
        __syncthreads();
        short8 fr[2], fc[2], fb[4];
        #pragma unroll
        for (int i = 0; i < 2; ++i) {
            fr[i] = *(const short8*)&Ar[(wm + i * 16 + lrow) * 32 + quad * 8];
            fc[i] = *(const short8*)&Ac[(wm + i * 16 + lrow) * 32 + quad * 8];
        }
        #pragma unroll
        for (int j = 0; j < 4; ++j) fb[j] = *(const short8*)&Bs[(wn + j * 16 + lrow) * 32 + quad * 8];
        #pragma unroll
        for (int i = 0; i < 2; ++i)
            #pragma unroll
            for (int j = 0; j < 4; ++j) {
                ar_[i][j] = MFMA_BF16(fr[i], fb[j], ar_[i][j], 0, 0, 0);
                ac_[i][j] = MFMA_BF16(fc[i], fb[j], ac_[i][j], 0, 0, 0);
            }
    }
    const float* tr = tbuf + ((size_t)2 * NB + b) * 512;
    const float* tc = tbuf + ((size_t)1 * NB + b) * 512;
    u16* out = scmb + (size_t)b * 512 * L;
    #pragma unroll
    for (int i = 0; i < 2; ++i)
        #pragma unroll
        for (int j = 0; j < 4; ++j) {
            int brow = l0 + wm + i * 16 + quad * 4;
            int col = m0 + wn + j * 16 + lrow;
            #pragma unroll
            for (int r = 0; r < 4; ++r) {
                float vv = (ar_[i][j][r] + tr[brow + r]) * SCALE
                         + tanhf((ac_[i][j][r] + tc[brow + r]) * SCALE);
                out[(size_t)(brow + r) * L + col] = f2b(vv);
            }
        }
}

// ---------------- K2b: per-row masked softmax, write P = g*softmax in place ----------------
__global__ __launch_bounds__(256) void k2b(u16* __restrict__ ssup,
        u16* __restrict__ scmb, const int* __restrict__ ids,
        const int* __restrict__ padp, const int* __restrict__ sepArr,
        const float* __restrict__ gate, const int* __restrict__ flag) {
    int b = blockIdx.y, l = blockIdx.x;
    int sep = sepArr[b];
    if (l >= sep) return;
    float g = gate[b * L + l];
    int is64 = flag[1];
    int pad = padp[0];
    int tid = threadIdx.x;
    __shared__ float red[256];
    float s0[4], s1[4];
    u16* rs = ssup + ((size_t)b * 512 + l) * L;
    u16* rc = scmb + ((size_t)b * 512 + l) * L;
    float mx0 = -3.4e38f, mx1 = -3.4e38f;
    for (int u = 0; u < 4; ++u) {
        int m = tid + u * 256;
        bool ok = (m > sep) && (ldid(ids, (size_t)b * L + m, is64) != pad);
        s0[u] = ok ? b2f(rs[m]) : NEGV;
        s1[u] = ok ? b2f(rc[m]) : NEGV;
        mx0 = fmaxf(mx0, s0[u]); mx1 = fmaxf(mx1, s1[u]);
    }
    red[tid] = mx0; __syncthreads();
    for (int s = 128; s > 0; s >>= 1) { if (tid < s) red[tid] = fmaxf(red[tid], red[tid + s]); __syncthreads(); }
    mx0 = red[0]; __syncthreads();
    red[tid] = mx1; __syncthreads();
    for (int s = 128; s > 0; s >>= 1) { if (tid < s) red[tid] = fmaxf(red[tid], red[tid + s]); __syncthreads(); }
    mx1 = red[0]; __syncthreads();
    float e0s = 0.f, e1s = 0.f;
    for (int u = 0; u < 4; ++u) {
        s0[u] = expf(s0[u] - mx0); e0s += s0[u];
        s1[u] = expf(s1[u] - mx1); e1s += s1[u];
    }
    red[tid] = e0s; __syncthreads();
    for (int s = 128; s > 0; s >>= 1) { if (tid < s) red[tid] += red[tid + s]; __syncthreads(); }
    float d0 = fmaxf(red[0], 1e-30f); __syncthreads();
    red[tid] = e1s; __syncthreads();
    for (int s = 128; s > 0; s >>= 1) { if (tid < s) red[tid] += red[tid + s]; __syncthreads(); }
    float d1 = fmaxf(red[0], 1e-30f);
    float i0 = g / d0, i1 = g / d1;
    for (int u = 0; u < 4; ++u) {
        int m = tid + u * 256;
        rs[m] = f2b(s0[u] * i0);
        rc[m] = f2b(s1[u] * i1);
    }
}

// ---------------- kcol: csup[m] = sum_{l<sep} P0[l][m]; crep likewise ----------------
__global__ __launch_bounds__(256) void kcol(const u16* __restrict__ ssup,
        const u16* __restrict__ scmb, const int* __restrict__ sepArr,
        float* __restrict__ csup, float* __restrict__ crep) {
    __shared__ float r0s[256], r1s[256];
    int b = blockIdx.y, sep = sepArr[b];
    int tid = threadIdx.x;
    int m = blockIdx.x * 64 + (tid & 63);
    int q = tid >> 6;
    const u16* P0 = ssup + (size_t)b * 512 * L;
    const u16* P1 = scmb + (size_t)b * 512 * L;
    float s0 = 0.f, s1 = 0.f;
    for (int l = q; l < sep; l += 4) {
        s0 += b2f(P0[(size_t)l * L + m]);
        s1 += b2f(P1[(size_t)l * L + m]);
    }
    r0s[tid] = s0; r1s[tid] = s1; __syncthreads();
    if (q == 0) {
        s0 = r0s[tid] + r0s[tid + 64] + r0s[tid + 128] + r0s[tid + 192];
        s1 = r1s[tid] + r1s[tid + 64] + r1s[tid + 128] + r1s[tid + 192];
        csup[b * L + m] = s0; crep[b * L + m] = s1;
    }
}

// ---------------- K3: af/w_rep/w_sup weighted sums over x ----------------
template<int F32> __device__ void k3_body(const void* x, const float* gate,
        const float* csup, const float* crep, float* af, float* wrep, float* wsup) {
    int b = blockIdx.y, c = blockIdx.x;
    int tid = threadIdx.x;
    float a0 = 0.f, a1 = 0.f, a2 = 0.f;
    float r0 = 0.f, r1 = 0.f, r2 = 0.f;
    float q0 = 0.f, q1 = 0.f, q2 = 0.f;
    for (int mm = 0; mm < 128; ++mm) {
        int m = c * 128 + mm;
        float wg = gate[b * L + m], wr = crep[b * L + m], wq = csup[b * L + m];
        if (wg == 0.f && wr == 0.f && wq == 0.f) continue;
        size_t base = ((size_t)b * L + m) * D;
        float x0 = ld1<F32>(x, base + tid);
        float x1 = ld1<F32>(x, base + tid + 256);
        float x2 = ld1<F32>(x, base + tid + 512);
        a0 += wg * x0; a1 += wg * x1; a2 += wg * x2;
        r0 += wr * x0; r1 += wr * x1; r2 += wr * x2;
        q0 += wq * x0; q1 += wq * x1; q2 += wq * x2;
    }
    atomicAdd(&af[b * D + tid], a0); atomicAdd(&af[b * D + tid + 256], a1); atomicAdd(&af[b * D + tid + 512], a2);
    atomicAdd(&wrep[b * D + tid], r0); atomicAdd(&wrep[b * D + tid + 256], r1); atomicAdd(&wrep[b * D + tid + 512], r2);
    atomicAdd(&wsup[b * D + tid], q0); atomicAdd(&wsup[b * D + tid + 256], q1); atomicAdd(&wsup[b * D + tid + 512], q2);
}
__global__ __launch_bounds__(256) void k3(const void* x, const float* gate,
        const float* csup, const float* crep, float* af, float* wrep, float* wsup,
        const int* flag) {
    if (flag[0]) k3_body<1>(x, gate, csup, crep, af, wrep, wsup);
    else         k3_body<0>(x, gate, csup, crep, af, wrep, wsup);
}

// ---------------- K4a: h = relu([af,wrep,wsup] @ Wf1 + bf1) ----------------
template<int F32> __device__ void k4a_body(const float* af, const float* wrep,
        const float* wsup, const void* Wf1, const void* bf1, float* h, float* fin) {
    int b = blockIdx.y;
    int j = blockIdx.x * 256 + threadIdx.x;
    int tid = threadIdx.x;
    for (int i = tid; i < D; i += 256) {
        fin[i] = af[b * D + i];
        fin[D + i] = wrep[b * D + i];
        fin[2 * D + i] = wsup[b * D + i];
    }
    __syncthreads();
    float acc = ld1<F32>(bf1, j);
    for (int i = 0; i < 3 * D; ++i) acc += fin[i] * ld1<F32>(Wf1, (size_t)i * D + j);
    h[b * D + j] = fmaxf(acc, 0.f);
}
__global__ __launch_bounds__(256) void k4a(const float* af, const float* wrep,
        const float* wsup, const void* Wf1, const void* bf1, float* h, const int* flag) {
    __shared__ float fin[3 * D];
    if (flag[0]) k4a_body<1>(af, wrep, wsup, Wf1, bf1, h, fin);
    else         k4a_body<0>(af, wrep, wsup, Wf1, bf1, h, fin);
}

// ---------------- K4b: out = LN(h @ Wf2 + bf2) * gamma + beta ----------------
template<int F32> __device__ void k4b_body(const float* h, const void* Wf2,
        const void* bf2, const void* gamma, const void* beta, void* out,
        float* hs, float* red) {
    int b = blockIdx.x, tid = threadIdx.x;
    for (int i = tid; i < D; i += 256) hs[i] = h[b * D + i];
    __syncthreads();
    float o[3];
    #pragma unroll
    for (int u = 0; u < 3; ++u) {
        int i = tid + u * 256;
        float acc = ld1<F32>(bf2, i);
        for (int j = 0; j < D; ++j) acc += hs[j] * ld1<F32>(Wf2, (size_t)j * D + i);
        o[u] = acc;
    }
    red[tid] = o[0] + o[1] + o[2]; __syncthreads();
    for (int s = 128; s > 0; s >>= 1) { if (tid < s) red[tid] += red[tid + s]; __syncthreads(); }
    float mu = red[0] / (float)D; __syncthreads();
    float vs = 0.f;
    #pragma unroll
    for (int u = 0; u < 3; ++u) vs += (o[u] - mu) * (o[u] - mu);
    red[tid] = vs; __syncthreads();
    for (int s = 128; s > 0; s >>= 1) { if (tid < s) red[tid] += red[tid + s]; __syncthreads(); }
    float var = red[0] / (float)D;
    float rstd = 1.0f / sqrtf(var + 1e-5f);
    #pragma unroll
    for (int u = 0; u < 3; ++u) {
        int i = tid + u * 256;
        float v = (o[u] - mu) * rstd * ld1<F32>(gamma, i) + ld1<F32>(beta, i);
        if (F32) ((float*)out)[b * D + i] = v;
        else     ((u16*)out)[b * D + i] = f2b(v);
    }
}
__global__ __launch_bounds__(256) void k4b(const float* h, const void* Wf2,
        const void* bf2, const void* gamma, const void* beta, void* out,
        const int* flag) {
    __shared__ float hs[D], red[256];
    if (flag[0]) k4b_body<1>(h, Wf2, bf2, gamma, beta, out, hs, red);
    else         k4b_body<0>(h, Wf2, bf2, gamma, beta, out, hs, red);
}

extern "C" void kernel_launch(void* const* d_in, const int* in_sizes, int n_in,
                              void* d_out, int out_size, void* d_ws, size_t ws_size,
                              hipStream_t stream) {
    const void* x    = d_in[0];
    const int* ids   = (const int*)d_in[1];
    const int* padp  = (const int*)d_in[2];
    const void* Wa   = d_in[3];
    const void* ba   = d_in[4];
    PP pp;
    pp.W[0] = d_in[5];  pp.b[0] = d_in[6];    // qs
    pp.W[1] = d_in[7];  pp.b[1] = d_in[8];    // ks
    pp.W[2] = d_in[9];  pp.b[2] = d_in[10];   // qc
    pp.W[3] = d_in[11]; pp.b[3] = d_in[12];   // kc
    pp.W[4] = d_in[13]; pp.b[4] = d_in[14];   // qr
    pp.W[5] = d_in[15]; pp.b[5] = d_in[16];   // kr
    const void* Wf1 = d_in[17]; const void* bf1 = d_in[18];
    const void* Wf2 = d_in[19]; const void* bf2 = d_in[20];
    const void* gamma = d_in[21]; const void* beta = d_in[22];

    char* ws = (char*)d_ws;
    int*   flag   = (int*)(ws + WS_FLAG);
    int*   sepArr = (int*)(ws + WS_SEP);
    float* c0   = (float*)(ws + WS_C0);
    float* z0   = (float*)(ws + WS_Z0);
    float* w1   = (float*)(ws + WS_W1);
    float* gate = (float*)(ws + WS_GATE);
    float* csup = (float*)(ws + WS_CSUP);
    float* crep = (float*)(ws + WS_CREP);
    float* af   = (float*)(ws + WS_AF);
    float* wrep = (float*)(ws + WS_WREP);
    float* wsup = (float*)(ws + WS_WSUP);
    float* h    = (float*)(ws + WS_H);
    float* alog = (float*)(ws + WS_ALOG);
    float* tbuf = (float*)(ws + WS_T);
    u16* xb   = (u16*)(ws + WS_XB);
    u16* Zbuf = (u16*)(ws + WS_Z);
    u16* Wb   = (u16*)(ws + WS_WB);
    u16* Mt   = (u16*)(ws + WS_M);
    u16* ssup = (u16*)(ws + WS_SSUP);
    u16* scmb = (u16*)(ws + WS_SCMB);

    kdetect<<<dim3(1), dim3(128), 0, stream>>>(x, ids, flag);
    kconvx<<<dim3(3072), dim3(256), 0, stream>>>(x, xb, flag);
    kconvw<<<dim3(288, 6), dim3(256), 0, stream>>>(pp, Wb, flag);
    k0a<<<dim3(NB * L / 64), dim3(256), 0, stream>>>(x, Wa, ba, alog, flag);
    k0b<<<dim3(NB), dim3(256), 0, stream>>>(ids, padp, alog, gate, sepArr,
                                            af, wrep, wsup, flag);
    kbias_row<<<dim3(12, 6), dim3(256), 0, stream>>>(pp, z0, w1, flag);
    kc0<<<dim3(3), dim3(256), 0, stream>>>(pp, c0, flag);
    kT<<<dim3(8, NB, 3), dim3(256), 0, stream>>>(x, w1, c0, tbuf, flag);
    kM_mfma<<<dim3(6, 6, 3), dim3(256), 0, stream>>>(Wb, Mt);
    kZ_mfma<<<dim3(6, 4, 24), dim3(256), 0, stream>>>(xb, Mt, z0, Zbuf, sepArr);
    kSsup_mfma<<<dim3(8, 4, NB), dim3(256), 0, stream>>>(Zbuf, xb, tbuf, sepArr, ssup);
    kScmb_mfma<<<dim3(8, 8, NB), dim3(256), 0, stream>>>(Zbuf, xb, tbuf, sepArr, scmb);
    k2b<<<dim3(512, NB), dim3(256), 0, stream>>>(ssup, scmb, ids, padp, sepArr, gate, flag);
    kcol<<<dim3(16, NB), dim3(256), 0, stream>>>(ssup, scmb, sepArr, csup, crep);
    k3<<<dim3(8, NB), dim3(256), 0, stream>>>(x, gate, csup, crep, af, wrep, wsup, flag);
    k4a<<<dim3(3, NB), dim3(256), 0, stream>>>(af, wrep, wsup, Wf1, bf1, h, flag);
    k4b<<<dim3(NB), dim3(256), 0, stream>>>(h, Wf2, bf2, gamma, beta, d_out, flag);
}

// Round 4
// 397.312 us; speedup vs baseline: 3.2399x; 1.3050x over previous
//
#include <hip/hip_runtime.h>
#include <math.h>

#define L 1024
#define NB 8
#define D 768
#define NEGV (-9.0e15f)
#define SCALE 0.036084391824351615f  // 1/sqrt(768)

typedef unsigned short u16;
typedef __attribute__((ext_vector_type(8))) short short8;
typedef __attribute__((ext_vector_type(4))) float float4v;
#define MFMA_BF16 __builtin_amdgcn_mfma_f32_16x16x32_bf16

__device__ __forceinline__ float b2f(u16 u) {
    union { unsigned int i; float f; } v; v.i = ((unsigned int)u) << 16; return v.f;
}
__device__ __forceinline__ u16 f2b(float f) {
    union { float fv; unsigned int i; } v; v.fv = f;
    unsigned int x = v.i;
    x += 0x7fffu + ((x >> 16) & 1u);   // RNE
    return (u16)(x >> 16);
}

template<int F32>
__device__ __forceinline__ float4 ld4(const void* p, size_t idx) {
    if (F32) return *(const float4*)((const float*)p + idx);
    ushort4 v = *(const ushort4*)((const u16*)p + idx);
    return make_float4(b2f(v.x), b2f(v.y), b2f(v.z), b2f(v.w));
}
template<int F32>
__device__ __forceinline__ float ld1(const void* p, size_t idx) {
    if (F32) return ((const float*)p)[idx];
    return b2f(((const u16*)p)[idx]);
}
__device__ __forceinline__ int ldid(const int* p, size_t idx, int is64) {
    return is64 ? p[idx * 2] : p[idx];
}

// ---------------- workspace layout (bytes) ----------------
#define WS_FLAG  ((size_t)0)
#define WS_SEP   ((size_t)64)
#define WS_C0    ((size_t)128)
#define WS_Z0    ((size_t)192)
#define WS_W1    ((size_t)9472)
#define WS_GATE  ((size_t)18752)
#define WS_CSUP  ((size_t)51520)
#define WS_CREP  ((size_t)84288)
#define WS_AF    ((size_t)117056)
#define WS_WREP  ((size_t)141632)
#define WS_WSUP  ((size_t)166208)
#define WS_HACC  ((size_t)190784)     // NB*D f32 = 24576 -> 215360
#define WS_ALOG  ((size_t)215360)
#define WS_T     ((size_t)248128)     // 3*NB*512 f32 -> ends 297280
#define WS_OACC  ((size_t)303104)     // NB*D f32 -> 327680
#define WS_XB    ((size_t)524288)     // NB*L*D bf16 = 12.58 MB -> 13107200
#define WS_Z     ((size_t)13107200)   // 3*NB*512*D bf16 = 18.87 MB -> 31981568
#define WS_SSUP  ((size_t)31981568)   // NB*512*L bf16 = 8.39 MB -> 40370176
#define WS_WB    WS_SSUP              // 6*D*D bf16 = 7.08 MB (dead before kSsup writes)
#define WS_SCMB  ((size_t)40370176)   // NB*512*L bf16 -> 48758784 (~46.5 MB total)
#define WS_M     WS_SCMB              // 3*D*D bf16 = 3.54 MB (dead before kScmb writes)

struct PP { const void* W[6]; const void* b[6]; };

// ---------------- detect dtypes ----------------
__global__ __launch_bounds__(128) void kdetect(const void* x, const void* ids, int* flag) {
    __shared__ int cnt[2];
    int tid = threadIdx.x;
    if (tid == 0) { cnt[0] = 0; cnt[1] = 0; }
    __syncthreads();
    if (tid < 64) {
        u16 u = ((const u16*)x)[tid * 2];
        int e = (u >> 7) & 0xFF;
        if (e >= 100 && e <= 140) atomicAdd(&cnt[0], 1);
    } else {
        int v = ((const int*)ids)[(tid - 64) * 2 + 1];
        if (v != 0) atomicAdd(&cnt[1], 1);
    }
    __syncthreads();
    if (tid == 0) {
        flag[0] = (cnt[0] < 32) ? 1 : 0;   // 1 => floats are f32
        flag[1] = (cnt[1] == 0) ? 1 : 0;   // 1 => ids are int64
    }
}

// ---------------- kconvx: x -> bf16 ----------------
__global__ __launch_bounds__(256) void kconvx(const void* x, u16* xb, const int* flag) {
    size_t base = ((size_t)blockIdx.x * 256 + threadIdx.x) * 8;
    if (flag[0]) {
        float4 a = *(const float4*)((const float*)x + base);
        float4 b = *(const float4*)((const float*)x + base + 4);
        uint4 o; u16* po = (u16*)&o;
        po[0] = f2b(a.x); po[1] = f2b(a.y); po[2] = f2b(a.z); po[3] = f2b(a.w);
        po[4] = f2b(b.x); po[5] = f2b(b.y); po[6] = f2b(b.z); po[7] = f2b(b.w);
        *(uint4*)(xb + base) = o;
    } else {
        *(uint4*)(xb + base) = *(const uint4*)((const u16*)x + base);
    }
}

// ---------------- kconvw: 6 weight matrices -> bf16 ----------------
__global__ __launch_bounds__(256) void kconvw(PP pp, u16* Wb, const int* flag) {
    int t = blockIdx.y;
    size_t base = ((size_t)blockIdx.x * 256 + threadIdx.x) * 8;
    u16* dst = Wb + (size_t)t * D * D;
    const void* src = pp.W[t];
    if (flag[0]) {
        float4 a = *(const float4*)((const float*)src + base);
        float4 b = *(const float4*)((const float*)src + base + 4);
        uint4 o; u16* po = (u16*)&o;
        po[0] = f2b(a.x); po[1] = f2b(a.y); po[2] = f2b(a.z); po[3] = f2b(a.w);
        po[4] = f2b(b.x); po[5] = f2b(b.y); po[6] = f2b(b.z); po[7] = f2b(b.w);
        *(uint4*)(dst + base) = o;
    } else {
        *(uint4*)(dst + base) = *(const uint4*)((const u16*)src + base);
    }
}

// ---------------- K0a: a_logits = x @ Wa + ba ----------------
template<int F32> __device__ void k0a_body(const void* x, const void* Wa,
        const void* ba, float* alog, float* was) {
    int tid = threadIdx.x;
    for (int i = tid; i < D; i += 256) was[i] = ld1<F32>(Wa, i);
    __syncthreads();
    int row = blockIdx.x * 64 + (tid >> 2);
    int sub = tid & 3;
    float acc = 0.f;
    for (int i = 0; i < 48; ++i) {
        int k = i * 16 + sub * 4;
        float4 xv = ld4<F32>(x, (size_t)row * D + k);
        acc += xv.x * was[k] + xv.y * was[k + 1] + xv.z * was[k + 2] + xv.w * was[k + 3];
    }
    acc += __shfl_xor(acc, 1);
    acc += __shfl_xor(acc, 2);
    if (sub == 0) alog[row] = acc + ld1<F32>(ba, 0);
}
__global__ __launch_bounds__(256) void k0a(const void* x, const void* Wa,
        const void* ba, float* alog, const int* flag) {
    __shared__ float was[D];
    if (flag[0]) k0a_body<1>(x, Wa, ba, alog, was);
    else         k0a_body<0>(x, Wa, ba, alog, was);
}

// ---------------- K0b: sep, gate softmax, zero accumulators ----------------
__global__ __launch_bounds__(256) void k0b(const int* __restrict__ ids,
        const int* __restrict__ padp, const float* __restrict__ alog,
        float* __restrict__ gate, int* __restrict__ sepArr,
        float* __restrict__ af, float* __restrict__ wrep, float* __restrict__ wsup,
        float* __restrict__ hacc, float* __restrict__ oacc,
        const int* __restrict__ flag) {
    __shared__ float red[256];
    __shared__ int sepSh;
    int is64 = flag[1];
    int b = blockIdx.x, tid = threadIdx.x;
    int pad = padp[0];
    int cnt = 0;
    for (int l = tid; l < L; l += 256) cnt += (ldid(ids, (size_t)b * L + l, is64) != pad) ? 1 : 0;
    red[tid] = (float)cnt; __syncthreads();
    for (int s = 128; s > 0; s >>= 1) { if (tid < s) red[tid] += red[tid + s]; __syncthreads(); }
    if (tid == 0) {
        int vl = (int)red[0];
        int sep = vl / 2; if (sep < 1) sep = 1; if (sep > L - 2) sep = L - 2;
        sepSh = sep; sepArr[b] = sep;
    }
    __syncthreads();
    int sep = sepSh;
    float lv[4]; int lidx[4];
    float mx = -3.4e38f;
    for (int u = 0; u < 4; ++u) {
        int l = tid + u * 256; lidx[u] = l;
        bool fm = (l < sep) && (ldid(ids, (size_t)b * L + l, is64) != pad);
        float v = fm ? alog[b * L + l] : NEGV;
        lv[u] = v; mx = fmaxf(mx, v);
    }
    red[tid] = mx; __syncthreads();
    for (int s = 128; s > 0; s >>= 1) { if (tid < s) red[tid] = fmaxf(red[tid], red[tid + s]); __syncthreads(); }
    mx = red[0]; __syncthreads();
    float se = 0.f;
    for (int u = 0; u < 4; ++u) { lv[u] = expf(lv[u] - mx); se += lv[u]; }
    red[tid] = se; __syncthreads();
    for (int s = 128; s > 0; s >>= 1) { if (tid < s) red[tid] += red[tid + s]; __syncthreads(); }
    float den = fmaxf(red[0], 1e-30f); __syncthreads();
    float gs = 0.f; float gv[4];
    for (int u = 0; u < 4; ++u) {
        int l = lidx[u];
        bool fm = (l < sep) && (ldid(ids, (size_t)b * L + l, is64) != pad);
        float p = lv[u] / den;
        gv[u] = fm ? p : 0.f;
        gs += gv[u];
    }
    red[tid] = gs; __syncthreads();
    for (int s = 128; s > 0; s >>= 1) { if (tid < s) red[tid] += red[tid + s]; __syncthreads(); }
    gs = red[0];
    float inv = 1.f / fmaxf(gs, 1e-8f);
    for (int u = 0; u < 4; ++u) gate[b * L + lidx[u]] = gv[u] * inv;
    for (int i = tid; i < D; i += 256) {
        af[b * D + i] = 0.f; wrep[b * D + i] = 0.f; wsup[b * D + i] = 0.f;
        hacc[b * D + i] = 0.f; oacc[b * D + i] = 0.f;
    }
}

// ---------------- kbias_row: z0 = Wk@bq (which=0), w1 = Wq@bk (which=1) ----------------
template<int F32> __device__ void kbias_body(const void* W, const void* vec,
        float* out, float* vs) {
    int tid = threadIdx.x;
    for (int i = tid; i < D; i += 256) vs[i] = ld1<F32>(vec, i);
    __syncthreads();
    int row = blockIdx.x * 64 + (tid >> 2);
    int sub = tid & 3;
    float acc = 0.f;
    for (int i = 0; i < 48; ++i) {
        int k = i * 16 + sub * 4;
        float4 wv = ld4<F32>(W, (size_t)row * D + k);
        acc += wv.x * vs[k] + wv.y * vs[k + 1] + wv.z * vs[k + 2] + wv.w * vs[k + 3];
    }
    acc += __shfl_xor(acc, 1);
    acc += __shfl_xor(acc, 2);
    if (sub == 0) out[row] = acc;
}
__global__ __launch_bounds__(256) void kbias_row(PP pp, float* z0, float* w1,
        const int* flag) {
    __shared__ float vs[D];
    int y = blockIdx.y;
    int p = y >> 1, which = y & 1;
    const void* W   = which ? pp.W[2 * p]     : pp.W[2 * p + 1];
    const void* vec = which ? pp.b[2 * p + 1] : pp.b[2 * p];
    float* out = (which ? w1 : z0) + p * D;
    if (flag[0]) kbias_body<1>(W, vec, out, vs);
    else         kbias_body<0>(W, vec, out, vs);
}

// ---------------- kc0: c0[p] = bq . bk ----------------
template<int F32> __device__ void kc0_body(const void* bq, const void* bk,
        float* c0, int p, float* red) {
    int tid = threadIdx.x;
    float s = 0.f;
    for (int i = tid; i < D; i += 256) s += ld1<F32>(bq, i) * ld1<F32>(bk, i);
    red[tid] = s; __syncthreads();
    for (int st = 128; st > 0; st >>= 1) { if (tid < st) red[tid] += red[tid + st]; __syncthreads(); }
    if (tid == 0) c0[p] = red[0];
}
__global__ __launch_bounds__(256) void kc0(PP pp, float* c0, const int* flag) {
    __shared__ float red[256];
    int p = blockIdx.x;
    if (flag[0]) kc0_body<1>(pp.b[2 * p], pp.b[2 * p + 1], c0, p, red);
    else         kc0_body<0>(pp.b[2 * p], pp.b[2 * p + 1], c0, p, red);
}

// ---------------- kT: t[p][b][l] = x_l . w1_p + c0_p  (l < 512) ----------------
template<int F32> __device__ void kT_body(const void* x, const float* w1,
        const float* c0, float* tbuf, float* w1s) {
    int tid = threadIdx.x;
    int b = blockIdx.y, p = blockIdx.z;
    for (int i = tid; i < D; i += 256) w1s[i] = w1[p * D + i];
    __syncthreads();
    int row = blockIdx.x * 64 + (tid >> 2);
    int sub = tid & 3;
    float acc = 0.f;
    for (int i = 0; i < 48; ++i) {
        int k = i * 16 + sub * 4;
        float4 xv = ld4<F32>(x, ((size_t)b * L + row) * D + k);
        acc += xv.x * w1s[k] + xv.y * w1s[k + 1] + xv.z * w1s[k + 2] + xv.w * w1s[k + 3];
    }
    acc += __shfl_xor(acc, 1);
    acc += __shfl_xor(acc, 2);
    if (sub == 0) tbuf[((size_t)p * NB + b) * 512 + row] = acc + c0[p];
}
__global__ __launch_bounds__(256) void kT(const void* x, const float* w1,
        const float* c0, float* tbuf, const int* flag) {
    __shared__ float w1s[D];
    if (flag[0]) kT_body<1>(x, w1, c0, tbuf, w1s);
    else         kT_body<0>(x, w1, c0, tbuf, w1s);
}

// ================= MFMA GEMM (A . B^T), BM=BN=128, BK=32 =================
__device__ __forceinline__ void stage128(const u16* __restrict__ G, size_t ld,
        int r0, int k0, u16* S, int tid) {
    int rowa = tid >> 2, koa = (tid & 3) << 3;
    *(uint4*)&S[rowa * 32 + koa] = *(const uint4*)&G[(size_t)(r0 + rowa) * ld + k0 + koa];
    *(uint4*)&S[(rowa + 64) * 32 + koa] = *(const uint4*)&G[(size_t)(r0 + rowa + 64) * ld + k0 + koa];
}

__device__ __forceinline__ void gemm_core128(const u16* __restrict__ A, size_t lda, int r0,
        const u16* __restrict__ B, size_t ldb, int c0, int K,
        u16* As, u16* Bs, float4v acc[4][4]) {
    int tid = threadIdx.x;
    int lane = tid & 63, wave = tid >> 6;
    int wm = (wave >> 1) << 6, wn = (wave & 1) << 6;
    int quad = lane >> 4, lrow = lane & 15;
    #pragma unroll
    for (int i = 0; i < 4; ++i)
        #pragma unroll
        for (int j = 0; j < 4; ++j) acc[i][j] = (float4v){0.f, 0.f, 0.f, 0.f};
    for (int k0 = 0; k0 < K; k0 += 32) {
        __syncthreads();
        stage128(A, lda, r0, k0, As, tid);
        stage128(B, ldb, c0, k0, Bs, tid);
        __syncthreads();
        short8 af[4], bf[4];
        #pragma unroll
        for (int i = 0; i < 4; ++i) af[i] = *(const short8*)&As[(wm + i * 16 + lrow) * 32 + quad * 8];
        #pragma unroll
        for (int j = 0; j < 4; ++j) bf[j] = *(const short8*)&Bs[(wn + j * 16 + lrow) * 32 + quad * 8];
        #pragma unroll
        for (int i = 0; i < 4; ++i)
            #pragma unroll
            for (int j = 0; j < 4; ++j)
                acc[i][j] = MFMA_BF16(af[i], bf[j], acc[i][j], 0, 0, 0);
    }
}

// kM: Mt[j][k'] = sum_c Wk[j][c] Wq[k'][c]
__global__ __launch_bounds__(256) void kM_mfma(const u16* __restrict__ Wb, u16* __restrict__ Mt) {
    __shared__ __align__(16) u16 As[128 * 32];
    __shared__ __align__(16) u16 Bs[128 * 32];
    int p = blockIdx.z;
    int r0 = blockIdx.y * 128, c0 = blockIdx.x * 128;
    float4v acc[4][4];
    gemm_core128(Wb + (size_t)(2 * p + 1) * D * D, D, r0,
                 Wb + (size_t)(2 * p) * D * D, D, c0, D, As, Bs, acc);
    int lane = threadIdx.x & 63, wave = threadIdx.x >> 6;
    int wm = (wave >> 1) << 6, wn = (wave & 1) << 6;
    int quad = lane >> 4, lrow = lane & 15;
    u16* out = Mt + (size_t)p * D * D;
    #pragma unroll
    for (int i = 0; i < 4; ++i)
        #pragma unroll
        for (int j = 0; j < 4; ++j) {
            int brow = r0 + wm + i * 16 + quad * 4;
            int col = c0 + wn + j * 16 + lrow;
            #pragma unroll
            for (int r = 0; r < 4; ++r)
                out[(size_t)(brow + r) * D + col] = f2b(acc[i][j][r]);
        }
}

// kZ: Z[l][j] = sum_k xb[l][k] Mt[j][k] + z0[j]
__global__ __launch_bounds__(256) void kZ_mfma(const u16* __restrict__ xb,
        const u16* __restrict__ Mt, const float* __restrict__ z0,
        u16* __restrict__ Zbuf, const int* __restrict__ sepArr) {
    __shared__ __align__(16) u16 As[128 * 32];
    __shared__ __align__(16) u16 Bs[128 * 32];
    int z = blockIdx.z;
    int p = z >> 3, b = z & 7;
    int sep = sepArr[b];
    int r0 = blockIdx.y * 128;
    if (r0 >= sep) return;
    int c0 = blockIdx.x * 128;
    float4v acc[4][4];
    gemm_core128(xb + (size_t)b * L * D, D, r0,
                 Mt + (size_t)p * D * D, D, c0, D, As, Bs, acc);
    int lane = threadIdx.x & 63, wave = threadIdx.x >> 6;
    int wm = (wave >> 1) << 6, wn = (wave & 1) << 6;
    int quad = lane >> 4, lrow = lane & 15;
    const float* z0p = z0 + p * D;
    u16* out = Zbuf + ((size_t)p * NB + b) * 512 * D;
    #pragma unroll
    for (int i = 0; i < 4; ++i)
        #pragma unroll
        for (int j = 0; j < 4; ++j) {
            int brow = r0 + wm + i * 16 + quad * 4;
            int col = c0 + wn + j * 16 + lrow;
            float zb = z0p[col];
            #pragma unroll
            for (int r = 0; r < 4; ++r)
                out[(size_t)(brow + r) * D + col] = f2b(acc[i][j][r] + zb);
        }
}

// kSsup: S[l][m] = (Z0[l].xb[m] + t[l]) * SCALE
__global__ __launch_bounds__(256) void kSsup_mfma(const u16* __restrict__ Zbuf,
        const u16* __restrict__ xb, const float* __restrict__ tbuf,
        const int* __restrict__ sepArr, u16* __restrict__ ssup) {
    __shared__ __align__(16) u16 As[128 * 32];
    __shared__ __align__(16) u16 Bs[128 * 32];
    int b = blockIdx.z;
    int sep = sepArr[b];
    int l0 = blockIdx.y * 128;
    if (l0 >= sep) return;
    int m0 = blockIdx.x * 128;
    if (m0 + 127 <= sep) return;
    float4v acc[4][4];
    gemm_core128(Zbuf + (size_t)b * 512 * D, D, l0,
                 xb + (size_t)b * L * D, D, m0, D, As, Bs, acc);
    int lane = threadIdx.x & 63, wave = threadIdx.x >> 6;
    int wm = (wave >> 1) << 6, wn = (wave & 1) << 6;
    int quad = lane >> 4, lrow = lane & 15;
    const float* tp = tbuf + (size_t)b * 512;   // p=0
    u16* out = ssup + (size_t)b * 512 * L;
    #pragma unroll
    for (int i = 0; i < 4; ++i)
        #pragma unroll
        for (int j = 0; j < 4; ++j) {
            int brow = l0 + wm + i * 16 + quad * 4;
            int col = m0 + wn + j * 16 + lrow;
            #pragma unroll
            for (int r = 0; r < 4; ++r)
                out[(size_t)(brow + r) * L + col] = f2b((acc[i][j][r] + tp[brow + r]) * SCALE);
        }
}

// kScmb: S[l][m] = (Zr.x + tr)*SCALE + tanh((Zc.x + tc)*SCALE), BM=64
__global__ __launch_bounds__(256) void kScmb_mfma(const u16* __restrict__ Zbuf,
        const u16* __restrict__ xb, const float* __restrict__ tbuf,
        const int* __restrict__ sepArr, u16* __restrict__ scmb) {
    __shared__ __align__(16) u16 Ar[64 * 32];
    __shared__ __align__(16) u16 Ac[64 * 32];
    __shared__ __align__(16) u16 Bs[128 * 32];
    int b = blockIdx.z;
    int sep = sepArr[b];
    int l0 = blockIdx.y * 64;
    if (l0 >= sep) return;
    int m0 = blockIdx.x * 128;
    if (m0 + 127 <= sep) return;
    const u16* Zr = Zbuf + ((size_t)2 * NB + b) * 512 * D;
    const u16* Zc = Zbuf + ((size_t)1 * NB + b) * 512 * D;
    const u16* X = xb + (size_t)b * L * D;
    int tid = threadIdx.x, lane = tid & 63, wave = tid >> 6;
    int wm = (wave >> 1) << 5, wn = (wave & 1) << 6;
    int quad = lane >> 4, lrow = lane & 15;
    float4v ar_[2][4], ac_[2][4];
    #pragma unroll
    for (int i = 0; i < 2; ++i)
        #pragma unroll
        for (int j = 0; j < 4; ++j) { ar_[i][j] = (float4v){0.f,0.f,0.f,0.f}; ac_[i][j] = (float4v){0.f,0.f,0.f,0.f}; }
    for (int k0 = 0; k0 < D; k0 += 32) {
        __syncthreads();
        {
            int row = tid >> 2, ko = (tid & 3) << 3;
            *(uint4*)&Ar[row * 32 + ko] = *(const uint4*)&Zr[(size_t)(l0 + row) * D + k0 + ko];
            *(uint4*)&Ac[row * 32 + ko] = *(const uint4*)&Zc[(size_t)(l0 + row) * D + k0 + ko];
        }
        stage128(X, D, m0, k0, Bs, tid);
        __syncthreads();
        short8 fr[2], fc[2], fb[4];
        #pragma unroll
        for (int i = 0; i < 2; ++i) {
            fr[i] = *(const short8*)&Ar[(wm + i * 16 + lrow) * 32 + quad * 8];
            fc[i] = *(const short8*)&Ac[(wm + i * 16 + lrow) * 32 + quad * 8];
        }
        #pragma unroll
        for (int j = 0; j < 4; ++j) fb[j] = *(const short8*)&Bs[(wn + j * 16 + lrow) * 32 + quad * 8];
        #pragma unroll
        for (int i = 0; i < 2; ++i)
            #pragma unroll
            for (int j = 0; j < 4; ++j) {
                ar_[i][j] = MFMA_BF16(fr[i], fb[j], ar_[i][j], 0, 0, 0);
                ac_[i][j] = MFMA_BF16(fc[i], fb[j], ac_[i][j], 0, 0, 0);
            }
    }
    const float* tr = tbuf + ((size_t)2 * NB + b) * 512;
    const float* tc = tbuf + ((size_t)1 * NB + b) * 512;
    u16* out = scmb + (size_t)b * 512 * L;
    #pragma unroll
    for (int i = 0; i < 2; ++i)
        #pragma unroll
        for (int j = 0; j < 4; ++j) {
            int brow = l0 + wm + i * 16 + quad * 4;
            int col = m0 + wn + j * 16 + lrow;
            #pragma unroll
            for (int r = 0; r < 4; ++r) {
                float vv = (ar_[i][j][r] + tr[brow + r]) * SCALE
                         + tanhf((ac_[i][j][r] + tc[brow + r]) * SCALE);
                out[(size_t)(brow + r) * L + col] = f2b(vv);
            }
        }
}

// ---------------- K2b: per-row masked softmax, write P = g*softmax in place ----------------
__global__ __launch_bounds__(256) void k2b(u16* __restrict__ ssup,
        u16* __restrict__ scmb, const int* __restrict__ ids,
        const int* __restrict__ padp, const int* __restrict__ sepArr,
        const float* __restrict__ gate, const int* __restrict__ flag) {
    int b = blockIdx.y, l = blockIdx.x;
    int sep = sepArr[b];
    if (l >= sep) return;
    float g = gate[b * L + l];
    int is64 = flag[1];
    int pad = padp[0];
    int tid = threadIdx.x;
    __shared__ float red[256];
    float s0[4], s1[4];
    u16* rs = ssup + ((size_t)b * 512 + l) * L;
    u16* rc = scmb + ((size_t)b * 512 + l) * L;
    float mx0 = -3.4e38f, mx1 = -3.4e38f;
    for (int u = 0; u < 4; ++u) {
        int m = tid + u * 256;
        bool ok = (m > sep) && (ldid(ids, (size_t)b * L + m, is64) != pad);
        s0[u] = ok ? b2f(rs[m]) : NEGV;
        s1[u] = ok ? b2f(rc[m]) : NEGV;
        mx0 = fmaxf(mx0, s0[u]); mx1 = fmaxf(mx1, s1[u]);
    }
    red[tid] = mx0; __syncthreads();
    for (int s = 128; s > 0; s >>= 1) { if (tid < s) red[tid] = fmaxf(red[tid], red[tid + s]); __syncthreads(); }
    mx0 = red[0]; __syncthreads();
    red[tid] = mx1; __syncthreads();
    for (int s = 128; s > 0; s >>= 1) { if (tid < s) red[tid] = fmaxf(red[tid], red[tid + s]); __syncthreads(); }
    mx1 = red[0]; __syncthreads();
    float e0s = 0.f, e1s = 0.f;
    for (int u = 0; u < 4; ++u) {
        s0[u] = expf(s0[u] - mx0); e0s += s0[u];
        s1[u] = expf(s1[u] - mx1); e1s += s1[u];
    }
    red[tid] = e0s; __syncthreads();
    for (int s = 128; s > 0; s >>= 1) { if (tid < s) red[tid] += red[tid + s]; __syncthreads(); }
    float d0 = fmaxf(red[0], 1e-30f); __syncthreads();
    red[tid] = e1s; __syncthreads();
    for (int s = 128; s > 0; s >>= 1) { if (tid < s) red[tid] += red[tid + s]; __syncthreads(); }
    float d1 = fmaxf(red[0], 1e-30f);
    float i0 = g / d0, i1 = g / d1;
    for (int u = 0; u < 4; ++u) {
        int m = tid + u * 256;
        rs[m] = f2b(s0[u] * i0);
        rc[m] = f2b(s1[u] * i1);
    }
}

// ---------------- kcol: csup[m] = sum_{l<sep} P0[l][m]; crep likewise ----------------
__global__ __launch_bounds__(256) void kcol(const u16* __restrict__ ssup,
        const u16* __restrict__ scmb, const int* __restrict__ sepArr,
        float* __restrict__ csup, float* __restrict__ crep) {
    __shared__ float r0s[256], r1s[256];
    int b = blockIdx.y, sep = sepArr[b];
    int tid = threadIdx.x;
    int m = blockIdx.x * 64 + (tid & 63);
    int q = tid >> 6;
    const u16* P0 = ssup + (size_t)b * 512 * L;
    const u16* P1 = scmb + (size_t)b * 512 * L;
    float s0 = 0.f, s1 = 0.f;
    for (int l = q; l < sep; l += 4) {
        s0 += b2f(P0[(size_t)l * L + m]);
        s1 += b2f(P1[(size_t)l * L + m]);
    }
    r0s[tid] = s0; r1s[tid] = s1; __syncthreads();
    if (q == 0) {
        s0 = r0s[tid] + r0s[tid + 64] + r0s[tid + 128] + r0s[tid + 192];
        s1 = r1s[tid] + r1s[tid + 64] + r1s[tid + 128] + r1s[tid + 192];
        csup[b * L + m] = s0; crep[b * L + m] = s1;
    }
}

// ---------------- K3: af/w_rep/w_sup weighted sums over x ----------------
template<int F32> __device__ void k3_body(const void* x, const float* gate,
        const float* csup, const float* crep, float* af, float* wrep, float* wsup) {
    int b = blockIdx.y, c = blockIdx.x;
    int tid = threadIdx.x;
    float a0 = 0.f, a1 = 0.f, a2 = 0.f;
    float r0 = 0.f, r1 = 0.f, r2 = 0.f;
    float q0 = 0.f, q1 = 0.f, q2 = 0.f;
    for (int mm = 0; mm < 128; ++mm) {
        int m = c * 128 + mm;
        float wg = gate[b * L + m], wr = crep[b * L + m], wq = csup[b * L + m];
        if (wg == 0.f && wr == 0.f && wq == 0.f) continue;
        size_t base = ((size_t)b * L + m) * D;
        float x0 = ld1<F32>(x, base + tid);
        float x1 = ld1<F32>(x, base + tid + 256);
        float x2 = ld1<F32>(x, base + tid + 512);
        a0 += wg * x0; a1 += wg * x1; a2 += wg * x2;
        r0 += wr * x0; r1 += wr * x1; r2 += wr * x2;
        q0 += wq * x0; q1 += wq * x1; q2 += wq * x2;
    }
    atomicAdd(&af[b * D + tid], a0); atomicAdd(&af[b * D + tid + 256], a1); atomicAdd(&af[b * D + tid + 512], a2);
    atomicAdd(&wrep[b * D + tid], r0); atomicAdd(&wrep[b * D + tid + 256], r1); atomicAdd(&wrep[b * D + tid + 512], r2);
    atomicAdd(&wsup[b * D + tid], q0); atomicAdd(&wsup[b * D + tid + 256], q1); atomicAdd(&wsup[b * D + tid + 512], q2);
}
__global__ __launch_bounds__(256) void k3(const void* x, const float* gate,
        const float* csup, const float* crep, float* af, float* wrep, float* wsup,
        const int* flag) {
    if (flag[0]) k3_body<1>(x, gate, csup, crep, af, wrep, wsup);
    else         k3_body<0>(x, gate, csup, crep, af, wrep, wsup);
}

// ---------------- kh1: hacc += fused @ Wf1 (split-K, 96 blocks) ----------------
template<int F32> __device__ void kh1_body(const float* af, const float* wrep,
        const float* wsup, const void* Wf1, float* hacc, float* fs) {
    int tid = threadIdx.x;
    int c0 = blockIdx.x * 128, k0 = blockIdx.y * 144;
    // stage fused[8][144] slice
    for (int e = tid; e < 8 * 144; e += 256) {
        int b = e / 144, kk = e - b * 144;
        int k = k0 + kk;
        float v = (k < D) ? af[b * D + k] : (k < 2 * D) ? wrep[b * D + k - D]
                                                        : wsup[b * D + k - 2 * D];
        fs[b * 144 + kk] = v;
    }
    __syncthreads();
    int col = c0 + (tid & 127);
    int kg = tid >> 7;   // 0 or 1
    float acc[NB];
    #pragma unroll
    for (int b = 0; b < NB; ++b) acc[b] = 0.f;
    #pragma unroll 4
    for (int r = 0; r < 72; ++r) {
        int kk = kg * 72 + r;
        float w = ld1<F32>(Wf1, (size_t)(k0 + kk) * D + col);
        #pragma unroll
        for (int b = 0; b < NB; ++b) acc[b] += fs[b * 144 + kk] * w;
    }
    #pragma unroll
    for (int b = 0; b < NB; ++b) atomicAdd(&hacc[b * D + col], acc[b]);
}
__global__ __launch_bounds__(256) void kh1(const float* af, const float* wrep,
        const float* wsup, const void* Wf1, float* hacc, const int* flag) {
    __shared__ float fs[8 * 144];
    if (flag[0]) kh1_body<1>(af, wrep, wsup, Wf1, hacc, fs);
    else         kh1_body<0>(af, wrep, wsup, Wf1, hacc, fs);
}

// ---------------- kh2: oacc += relu(hacc+bf1) @ Wf2 (split-K, 48 blocks) ----------------
template<int F32> __device__ void kh2_body(const float* hacc, const void* bf1,
        const void* Wf2, float* oacc, float* hsl) {
    int tid = threadIdx.x;
    int c0 = blockIdx.x * 128, k0 = blockIdx.y * 96;
    for (int e = tid; e < 8 * 96; e += 256) {
        int b = e / 96, kk = e - b * 96;
        int k = k0 + kk;
        hsl[b * 96 + kk] = fmaxf(hacc[b * D + k] + ld1<F32>(bf1, k), 0.f);
    }
    __syncthreads();
    int col = c0 + (tid & 127);
    int kg = tid >> 7;
    float acc[NB];
    #pragma unroll
    for (int b = 0; b < NB; ++b) acc[b] = 0.f;
    #pragma unroll 4
    for (int r = 0; r < 48; ++r) {
        int kk = kg * 48 + r;
        float w = ld1<F32>(Wf2, (size_t)(k0 + kk) * D + col);
        #pragma unroll
        for (int b = 0; b < NB; ++b) acc[b] += hsl[b * 96 + kk] * w;
    }
    #pragma unroll
    for (int b = 0; b < NB; ++b) atomicAdd(&oacc[b * D + col], acc[b]);
}
__global__ __launch_bounds__(256) void kh2(const float* hacc, const void* bf1,
        const void* Wf2, float* oacc, const int* flag) {
    __shared__ float hsl[8 * 96];
    if (flag[0]) kh2_body<1>(hacc, bf1, Wf2, oacc, hsl);
    else         kh2_body<0>(hacc, bf1, Wf2, oacc, hsl);
}

// ---------------- kln: out = LN(oacc + bf2) * gamma + beta ----------------
template<int F32> __device__ void kln_body(const float* oacc, const void* bf2,
        const void* gamma, const void* beta, void* out, float* red) {
    int b = blockIdx.x, tid = threadIdx.x;
    float o[3];
    #pragma unroll
    for (int u = 0; u < 3; ++u) {
        int i = tid + u * 256;
        o[u] = oacc[b * D + i] + ld1<F32>(bf2, i);
    }
    red[tid] = o[0] + o[1] + o[2]; __syncthreads();
    for (int s = 128; s > 0; s >>= 1) { if (tid < s) red[tid] += red[tid + s]; __syncthreads(); }
    float mu = red[0] / (float)D; __syncthreads();
    float vs = 0.f;
    #pragma unroll
    for (int u = 0; u < 3; ++u) vs += (o[u] - mu) * (o[u] - mu);
    red[tid] = vs; __syncthreads();
    for (int s = 128; s > 0; s >>= 1) { if (tid < s) red[tid] += red[tid + s]; __syncthreads(); }
    float var = red[0] / (float)D;
    float rstd = 1.0f / sqrtf(var + 1e-5f);
    #pragma unroll
    for (int u = 0; u < 3; ++u) {
        int i = tid + u * 256;
        float v = (o[u] - mu) * rstd * ld1<F32>(gamma, i) + ld1<F32>(beta, i);
        if (F32) ((float*)out)[b * D + i] = v;
        else     ((u16*)out)[b * D + i] = f2b(v);
    }
}
__global__ __launch_bounds__(256) void kln(const float* oacc, const void* bf2,
        const void* gamma, const void* beta, void* out, const int* flag) {
    __shared__ float red[256];
    if (flag[0]) kln_body<1>(oacc, bf2, gamma, beta, out, red);
    else         kln_body<0>(oacc, bf2, gamma, beta, out, red);
}

extern "C" void kernel_launch(void* const* d_in, const int* in_sizes, int n_in,
                              void* d_out, int out_size, void* d_ws, size_t ws_size,
                              hipStream_t stream) {
    const void* x    = d_in[0];
    const int* ids   = (const int*)d_in[1];
    const int* padp  = (const int*)d_in[2];
    const void* Wa   = d_in[3];
    const void* ba   = d_in[4];
    PP pp;
    pp.W[0] = d_in[5];  pp.b[0] = d_in[6];    // qs
    pp.W[1] = d_in[7];  pp.b[1] = d_in[8];    // ks
    pp.W[2] = d_in[9];  pp.b[2] = d_in[10];   // qc
    pp.W[3] = d_in[11]; pp.b[3] = d_in[12];   // kc
    pp.W[4] = d_in[13]; pp.b[4] = d_in[14];   // qr
    pp.W[5] = d_in[15]; pp.b[5] = d_in[16];   // kr
    const void* Wf1 = d_in[17]; const void* bf1 = d_in[18];
    const void* Wf2 = d_in[19]; const void* bf2 = d_in[20];
    const void* gamma = d_in[21]; const void* beta = d_in[22];

    char* ws = (char*)d_ws;
    int*   flag   = (int*)(ws + WS_FLAG);
    int*   sepArr = (int*)(ws + WS_SEP);
    float* c0   = (float*)(ws + WS_C0);
    float* z0   = (float*)(ws + WS_Z0);
    float* w1   = (float*)(ws + WS_W1);
    float* gate = (float*)(ws + WS_GATE);
    float* csup = (float*)(ws + WS_CSUP);
    float* crep = (float*)(ws + WS_CREP);
    float* af   = (float*)(ws + WS_AF);
    float* wrep = (float*)(ws + WS_WREP);
    float* wsup = (float*)(ws + WS_WSUP);
    float* hacc = (float*)(ws + WS_HACC);
    float* oacc = (float*)(ws + WS_OACC);
    float* alog = (float*)(ws + WS_ALOG);
    float* tbuf = (float*)(ws + WS_T);
    u16* xb   = (u16*)(ws + WS_XB);
    u16* Zbuf = (u16*)(ws + WS_Z);
    u16* Wb   = (u16*)(ws + WS_WB);
    u16* Mt   = (u16*)(ws + WS_M);
    u16* ssup = (u16*)(ws + WS_SSUP);
    u16* scmb = (u16*)(ws + WS_SCMB);

    kdetect<<<dim3(1), dim3(128), 0, stream>>>(x, ids, flag);
    kconvx<<<dim3(3072), dim3(256), 0, stream>>>(x, xb, flag);
    kconvw<<<dim3(288, 6), dim3(256), 0, stream>>>(pp, Wb, flag);
    k0a<<<dim3(NB * L / 64), dim3(256), 0, stream>>>(x, Wa, ba, alog, flag);
    k0b<<<dim3(NB), dim3(256), 0, stream>>>(ids, padp, alog, gate, sepArr,
                                            af, wrep, wsup, hacc, oacc, flag);
    kbias_row<<<dim3(12, 6), dim3(256), 0, stream>>>(pp, z0, w1, flag);
    kc0<<<dim3(3), dim3(256), 0, stream>>>(pp, c0, flag);
    kT<<<dim3(8, NB, 3), dim3(256), 0, stream>>>(x, w1, c0, tbuf, flag);
    kM_mfma<<<dim3(6, 6, 3), dim3(256), 0, stream>>>(Wb, Mt);
    kZ_mfma<<<dim3(6, 4, 24), dim3(256), 0, stream>>>(xb, Mt, z0, Zbuf, sepArr);
    kSsup_mfma<<<dim3(8, 4, NB), dim3(256), 0, stream>>>(Zbuf, xb, tbuf, sepArr, ssup);
    kScmb_mfma<<<dim3(8, 8, NB), dim3(256), 0, stream>>>(Zbuf, xb, tbuf, sepArr, scmb);
    k2b<<<dim3(512, NB), dim3(256), 0, stream>>>(ssup, scmb, ids, padp, sepArr, gate, flag);
    kcol<<<dim3(16, NB), dim3(256), 0, stream>>>(ssup, scmb, sepArr, csup, crep);
    k3<<<dim3(8, NB), dim3(256), 0, stream>>>(x, gate, csup, crep, af, wrep, wsup, flag);
    kh1<<<dim3(6, 16), dim3(256), 0, stream>>>(af, wrep, wsup, Wf1, hacc, flag);
    kh2<<<dim3(6, 8), dim3(256), 0, stream>>>(hacc, bf1, Wf2, oacc, flag);
    kln<<<dim3(NB), dim3(256), 0, stream>>>(oacc, bf2, gamma, beta, d_out, flag);
}

// Round 5
// 331.565 us; speedup vs baseline: 3.8824x; 1.1983x over previous
//
#include <hip/hip_runtime.h>
#include <math.h>

#define L 1024
#define NB 8
#define D 768
#define NEGV (-9.0e15f)
#define SCALE 0.036084391824351615f  // 1/sqrt(768)

typedef unsigned short u16;
typedef __attribute__((ext_vector_type(8))) short short8;
typedef __attribute__((ext_vector_type(4))) float float4v;
#define MFMA_BF16 __builtin_amdgcn_mfma_f32_16x16x32_bf16

__device__ __forceinline__ float b2f(u16 u) {
    union { unsigned int i; float f; } v; v.i = ((unsigned int)u) << 16; return v.f;
}
__device__ __forceinline__ u16 f2b(float f) {
    union { float fv; unsigned int i; } v; v.fv = f;
    unsigned int x = v.i;
    x += 0x7fffu + ((x >> 16) & 1u);   // RNE
    return (u16)(x >> 16);
}

template<int F32>
__device__ __forceinline__ float4 ld4(const void* p, size_t idx) {
    if (F32) return *(const float4*)((const float*)p + idx);
    ushort4 v = *(const ushort4*)((const u16*)p + idx);
    return make_float4(b2f(v.x), b2f(v.y), b2f(v.z), b2f(v.w));
}
template<int F32>
__device__ __forceinline__ float ld1(const void* p, size_t idx) {
    if (F32) return ((const float*)p)[idx];
    return b2f(((const u16*)p)[idx]);
}
__device__ __forceinline__ int ldid(const int* p, size_t idx, int is64) {
    return is64 ? p[idx * 2] : p[idx];
}

// ---------------- workspace layout (bytes) ----------------
#define WS_FLAG  ((size_t)0)
#define WS_SEP   ((size_t)64)
#define WS_C0    ((size_t)128)
#define WS_Z0    ((size_t)192)
#define WS_W1    ((size_t)9472)
#define WS_GATE  ((size_t)18752)
#define WS_CSUP  ((size_t)51520)
#define WS_CREP  ((size_t)84288)
#define WS_AF    ((size_t)117056)
#define WS_WREP  ((size_t)141632)
#define WS_WSUP  ((size_t)166208)
#define WS_HACC  ((size_t)190784)
#define WS_ALOG  ((size_t)215360)
#define WS_T     ((size_t)248128)     // 3*NB*512 f32 -> ends 297280
#define WS_OACC  ((size_t)303104)
#define WS_XB    ((size_t)524288)     // NB*L*D bf16 -> 13107200
#define WS_Z     ((size_t)13107200)   // 3*NB*512*D bf16 -> 31981568
#define WS_SSUP  ((size_t)31981568)   // NB*512*L bf16 -> 40370176
#define WS_WB    WS_SSUP              // 6*D*D bf16 (dead before kSsup writes)
#define WS_SCMB  ((size_t)40370176)   // NB*512*L bf16 -> 48758784
#define WS_M     WS_SCMB              // 3*D*D bf16 (dead before kScmb writes)

struct PP { const void* W[6]; const void* b[6]; };

// ---------------- detect dtypes ----------------
__global__ __launch_bounds__(128) void kdetect(const void* x, const void* ids, int* flag) {
    __shared__ int cnt[2];
    int tid = threadIdx.x;
    if (tid == 0) { cnt[0] = 0; cnt[1] = 0; }
    __syncthreads();
    if (tid < 64) {
        u16 u = ((const u16*)x)[tid * 2];
        int e = (u >> 7) & 0xFF;
        if (e >= 100 && e <= 140) atomicAdd(&cnt[0], 1);
    } else {
        int v = ((const int*)ids)[(tid - 64) * 2 + 1];
        if (v != 0) atomicAdd(&cnt[1], 1);
    }
    __syncthreads();
    if (tid == 0) {
        flag[0] = (cnt[0] < 32) ? 1 : 0;   // 1 => floats are f32
        flag[1] = (cnt[1] == 0) ? 1 : 0;   // 1 => ids are int64
    }
}

// ---------------- kconv: x -> xb (bf16), 6 W -> Wb (bf16), fused ----------------
__global__ __launch_bounds__(256) void kconv(const void* x, PP pp, u16* xb, u16* Wb,
        const int* flag) {
    int bid = blockIdx.x;
    const void* src; u16* dst; size_t base;
    if (bid < 3072) {
        src = x; dst = xb;
        base = ((size_t)bid * 256 + threadIdx.x) * 8;
    } else {
        int t = (bid - 3072) / 288, inner = (bid - 3072) % 288;
        src = pp.W[t]; dst = Wb + (size_t)t * D * D;
        base = ((size_t)inner * 256 + threadIdx.x) * 8;
    }
    if (flag[0]) {
        float4 a = *(const float4*)((const float*)src + base);
        float4 b = *(const float4*)((const float*)src + base + 4);
        uint4 o; u16* po = (u16*)&o;
        po[0] = f2b(a.x); po[1] = f2b(a.y); po[2] = f2b(a.z); po[3] = f2b(a.w);
        po[4] = f2b(b.x); po[5] = f2b(b.y); po[6] = f2b(b.z); po[7] = f2b(b.w);
        *(uint4*)(dst + base) = o;
    } else {
        *(uint4*)(dst + base) = *(const uint4*)((const u16*)src + base);
    }
}

// ---------------- kbias_row: z0 = Wk@bq (which=0), w1 = Wq@bk (which=1) ----------------
template<int F32> __device__ void kbias_body(const void* W, const void* vec,
        float* out, float* vs) {
    int tid = threadIdx.x;
    for (int i = tid; i < D; i += 256) vs[i] = ld1<F32>(vec, i);
    __syncthreads();
    int row = blockIdx.x * 64 + (tid >> 2);
    int sub = tid & 3;
    float acc = 0.f;
    for (int i = 0; i < 48; ++i) {
        int k = i * 16 + sub * 4;
        float4 wv = ld4<F32>(W, (size_t)row * D + k);
        acc += wv.x * vs[k] + wv.y * vs[k + 1] + wv.z * vs[k + 2] + wv.w * vs[k + 3];
    }
    acc += __shfl_xor(acc, 1);
    acc += __shfl_xor(acc, 2);
    if (sub == 0) out[row] = acc;
}
__global__ __launch_bounds__(256) void kbias_row(PP pp, float* z0, float* w1,
        const int* flag) {
    __shared__ float vs[D];
    int y = blockIdx.y;
    int p = y >> 1, which = y & 1;
    const void* W   = which ? pp.W[2 * p]     : pp.W[2 * p + 1];
    const void* vec = which ? pp.b[2 * p + 1] : pp.b[2 * p];
    float* out = (which ? w1 : z0) + p * D;
    if (flag[0]) kbias_body<1>(W, vec, out, vs);
    else         kbias_body<0>(W, vec, out, vs);
}

// ---------------- kc0: c0[p] = bq . bk ----------------
template<int F32> __device__ void kc0_body(const void* bq, const void* bk,
        float* c0, int p, float* red) {
    int tid = threadIdx.x;
    float s = 0.f;
    for (int i = tid; i < D; i += 256) s += ld1<F32>(bq, i) * ld1<F32>(bk, i);
    red[tid] = s; __syncthreads();
    for (int st = 128; st > 0; st >>= 1) { if (tid < st) red[tid] += red[tid + st]; __syncthreads(); }
    if (tid == 0) c0[p] = red[0];
}
__global__ __launch_bounds__(256) void kc0(PP pp, float* c0, const int* flag) {
    __shared__ float red[256];
    int p = blockIdx.x;
    if (flag[0]) kc0_body<1>(pp.b[2 * p], pp.b[2 * p + 1], c0, p, red);
    else         kc0_body<0>(pp.b[2 * p], pp.b[2 * p + 1], c0, p, red);
}

// ---------------- kdots: fused a_logits + t[p] — reads x ONCE ----------------
// row dots: alog = x.Wa + ba ; t[p][b][l] = x.w1[p] + c0[p] (l<512)
template<int F32> __device__ void kdots_body(const void* x, const void* Wa,
        const void* ba, const float* w1, const float* c0, float* alog,
        float* tbuf, float* ws4) {
    int tid = threadIdx.x;
    for (int i = tid; i < D; i += 256) {
        ws4[i]         = ld1<F32>(Wa, i);
        ws4[D + i]     = w1[i];
        ws4[2 * D + i] = w1[D + i];
        ws4[3 * D + i] = w1[2 * D + i];
    }
    __syncthreads();
    int row = blockIdx.x * 32 + (tid >> 3);   // global row in [0, NB*L)
    int sub = tid & 7;
    float a0 = 0.f, a1 = 0.f, a2 = 0.f, a3 = 0.f;
    for (int i = 0; i < 24; ++i) {
        int k = i * 32 + sub * 4;
        float4 xv = ld4<F32>(x, (size_t)row * D + k);
        a0 += xv.x * ws4[k] + xv.y * ws4[k + 1] + xv.z * ws4[k + 2] + xv.w * ws4[k + 3];
        a1 += xv.x * ws4[D + k] + xv.y * ws4[D + k + 1] + xv.z * ws4[D + k + 2] + xv.w * ws4[D + k + 3];
        a2 += xv.x * ws4[2 * D + k] + xv.y * ws4[2 * D + k + 1] + xv.z * ws4[2 * D + k + 2] + xv.w * ws4[2 * D + k + 3];
        a3 += xv.x * ws4[3 * D + k] + xv.y * ws4[3 * D + k + 1] + xv.z * ws4[3 * D + k + 2] + xv.w * ws4[3 * D + k + 3];
    }
    #pragma unroll
    for (int d = 1; d < 8; d <<= 1) {
        a0 += __shfl_xor(a0, d); a1 += __shfl_xor(a1, d);
        a2 += __shfl_xor(a2, d); a3 += __shfl_xor(a3, d);
    }
    int b = row >> 10, l = row & 1023;
    if (sub == 0) alog[row] = a0 + ld1<F32>(ba, 0);
    else if (sub == 1 && l < 512) tbuf[((size_t)0 * NB + b) * 512 + l] = a1 + c0[0];
    else if (sub == 2 && l < 512) tbuf[((size_t)1 * NB + b) * 512 + l] = a2 + c0[1];
    else if (sub == 3 && l < 512) tbuf[((size_t)2 * NB + b) * 512 + l] = a3 + c0[2];
}
__global__ __launch_bounds__(256) void kdots(const void* x, const void* Wa,
        const void* ba, const float* w1, const float* c0, float* alog,
        float* tbuf, const int* flag) {
    __shared__ float ws4[4 * D];
    if (flag[0]) kdots_body<1>(x, Wa, ba, w1, c0, alog, tbuf, ws4);
    else         kdots_body<0>(x, Wa, ba, w1, c0, alog, tbuf, ws4);
}

// ---------------- K0b: sep, gate softmax, zero accumulators ----------------
__global__ __launch_bounds__(256) void k0b(const int* __restrict__ ids,
        const int* __restrict__ padp, const float* __restrict__ alog,
        float* __restrict__ gate, int* __restrict__ sepArr,
        float* __restrict__ af, float* __restrict__ wrep, float* __restrict__ wsup,
        float* __restrict__ hacc, float* __restrict__ oacc,
        const int* __restrict__ flag) {
    __shared__ float red[256];
    __shared__ int sepSh;
    int is64 = flag[1];
    int b = blockIdx.x, tid = threadIdx.x;
    int pad = padp[0];
    int cnt = 0;
    for (int l = tid; l < L; l += 256) cnt += (ldid(ids, (size_t)b * L + l, is64) != pad) ? 1 : 0;
    red[tid] = (float)cnt; __syncthreads();
    for (int s = 128; s > 0; s >>= 1) { if (tid < s) red[tid] += red[tid + s]; __syncthreads(); }
    if (tid == 0) {
        int vl = (int)red[0];
        int sep = vl / 2; if (sep < 1) sep = 1; if (sep > L - 2) sep = L - 2;
        sepSh = sep; sepArr[b] = sep;
    }
    __syncthreads();
    int sep = sepSh;
    float lv[4]; int lidx[4];
    float mx = -3.4e38f;
    for (int u = 0; u < 4; ++u) {
        int l = tid + u * 256; lidx[u] = l;
        bool fm = (l < sep) && (ldid(ids, (size_t)b * L + l, is64) != pad);
        float v = fm ? alog[b * L + l] : NEGV;
        lv[u] = v; mx = fmaxf(mx, v);
    }
    red[tid] = mx; __syncthreads();
    for (int s = 128; s > 0; s >>= 1) { if (tid < s) red[tid] = fmaxf(red[tid], red[tid + s]); __syncthreads(); }
    mx = red[0]; __syncthreads();
    float se = 0.f;
    for (int u = 0; u < 4; ++u) { lv[u] = expf(lv[u] - mx); se += lv[u]; }
    red[tid] = se; __syncthreads();
    for (int s = 128; s > 0; s >>= 1) { if (tid < s) red[tid] += red[tid + s]; __syncthreads(); }
    float den = fmaxf(red[0], 1e-30f); __syncthreads();
    float gs = 0.f; float gv[4];
    for (int u = 0; u < 4; ++u) {
        int l = lidx[u];
        bool fm = (l < sep) && (ldid(ids, (size_t)b * L + l, is64) != pad);
        float p = lv[u] / den;
        gv[u] = fm ? p : 0.f;
        gs += gv[u];
    }
    red[tid] = gs; __syncthreads();
    for (int s = 128; s > 0; s >>= 1) { if (tid < s) red[tid] += red[tid + s]; __syncthreads(); }
    gs = red[0];
    float inv = 1.f / fmaxf(gs, 1e-8f);
    for (int u = 0; u < 4; ++u) gate[b * L + lidx[u]] = gv[u] * inv;
    for (int i = tid; i < D; i += 256) {
        af[b * D + i] = 0.f; wrep[b * D + i] = 0.f; wsup[b * D + i] = 0.f;
        hacc[b * D + i] = 0.f; oacc[b * D + i] = 0.f;
    }
}

// ================= MFMA GEMM (A . B^T), async global->LDS staging =================
// LDS tile layout: row-major [rows][32] u16; thread tid stages 16 B at byte
// offset tid*16 == (tid>>2)*64 + (tid&3)*16, so wave-uniform base + lane*16
// matches exactly (global_load_lds requirement).
__device__ __forceinline__ void stage128_async(const u16* __restrict__ G, size_t ld,
        int r0, int k0, u16* S, int tid) {
    int rowa = tid >> 2, koa = (tid & 3) << 3;
    int wave = tid >> 6;
    const u16* g1 = &G[(size_t)(r0 + rowa) * ld + k0 + koa];
    const u16* g2 = &G[(size_t)(r0 + rowa + 64) * ld + k0 + koa];
    __builtin_amdgcn_global_load_lds((__attribute__((address_space(1))) void*)(u16*)g1,
        (__attribute__((address_space(3))) void*)(S + wave * 512), 16, 0, 0);
    __builtin_amdgcn_global_load_lds((__attribute__((address_space(1))) void*)(u16*)g2,
        (__attribute__((address_space(3))) void*)(S + 2048 + wave * 512), 16, 0, 0);
}
__device__ __forceinline__ void stage64_async(const u16* __restrict__ G, size_t ld,
        int r0, int k0, u16* S, int tid) {
    int rowa = tid >> 2, koa = (tid & 3) << 3;
    int wave = tid >> 6;
    const u16* g = &G[(size_t)(r0 + rowa) * ld + k0 + koa];
    __builtin_amdgcn_global_load_lds((__attribute__((address_space(1))) void*)(u16*)g,
        (__attribute__((address_space(3))) void*)(S + wave * 512), 16, 0, 0);
}

__device__ __forceinline__ void gemm_core128(const u16* __restrict__ A, size_t lda, int r0,
        const u16* __restrict__ B, size_t ldb, int c0, int K,
        u16* As, u16* Bs, float4v acc[4][4]) {
    int tid = threadIdx.x;
    int lane = tid & 63, wave = tid >> 6;
    int wm = (wave >> 1) << 6, wn = (wave & 1) << 6;
    int quad = lane >> 4, lrow = lane & 15;
    #pragma unroll
    for (int i = 0; i < 4; ++i)
        #pragma unroll
        for (int j = 0; j < 4; ++j) acc[i][j] = (float4v){0.f, 0.f, 0.f, 0.f};
    for (int k0 = 0; k0 < K; k0 += 32) {
        __syncthreads();
        stage128_async(A, lda, r0, k0, As, tid);
        stage128_async(B, ldb, c0, k0, Bs, tid);
        __syncthreads();
        short8 af[4], bf[4];
        #pragma unroll
        for (int i = 0; i < 4; ++i) af[i] = *(const short8*)&As[(wm + i * 16 + lrow) * 32 + quad * 8];
        #pragma unroll
        for (int j = 0; j < 4; ++j) bf[j] = *(const short8*)&Bs[(wn + j * 16 + lrow) * 32 + quad * 8];
        #pragma unroll
        for (int i = 0; i < 4; ++i)
            #pragma unroll
            for (int j = 0; j < 4; ++j)
                acc[i][j] = MFMA_BF16(af[i], bf[j], acc[i][j], 0, 0, 0);
    }
}

// kM: Mt[j][k'] = sum_c Wk[j][c] Wq[k'][c]
__global__ __launch_bounds__(256) void kM_mfma(const u16* __restrict__ Wb, u16* __restrict__ Mt) {
    __shared__ __align__(16) u16 As[128 * 32];
    __shared__ __align__(16) u16 Bs[128 * 32];
    int p = blockIdx.z;
    int r0 = blockIdx.y * 128, c0 = blockIdx.x * 128;
    float4v acc[4][4];
    gemm_core128(Wb + (size_t)(2 * p + 1) * D * D, D, r0,
                 Wb + (size_t)(2 * p) * D * D, D, c0, D, As, Bs, acc);
    int lane = threadIdx.x & 63, wave = threadIdx.x >> 6;
    int wm = (wave >> 1) << 6, wn = (wave & 1) << 6;
    int quad = lane >> 4, lrow = lane & 15;
    u16* out = Mt + (size_t)p * D * D;
    #pragma unroll
    for (int i = 0; i < 4; ++i)
        #pragma unroll
        for (int j = 0; j < 4; ++j) {
            int brow = r0 + wm + i * 16 + quad * 4;
            int col = c0 + wn + j * 16 + lrow;
            #pragma unroll
            for (int r = 0; r < 4; ++r)
                out[(size_t)(brow + r) * D + col] = f2b(acc[i][j][r]);
        }
}

// kZ: Z[l][j] = sum_k xb[l][k] Mt[j][k] + z0[j]
__global__ __launch_bounds__(256) void kZ_mfma(const u16* __restrict__ xb,
        const u16* __restrict__ Mt, const float* __restrict__ z0,
        u16* __restrict__ Zbuf, const int* __restrict__ sepArr) {
    __shared__ __align__(16) u16 As[128 * 32];
    __shared__ __align__(16) u16 Bs[128 * 32];
    int z = blockIdx.z;
    int p = z >> 3, b = z & 7;
    int sep = sepArr[b];
    int r0 = blockIdx.y * 128;
    if (r0 >= sep) return;
    int c0 = blockIdx.x * 128;
    float4v acc[4][4];
    gemm_core128(xb + (size_t)b * L * D, D, r0,
                 Mt + (size_t)p * D * D, D, c0, D, As, Bs, acc);
    int lane = threadIdx.x & 63, wave = threadIdx.x >> 6;
    int wm = (wave >> 1) << 6, wn = (wave & 1) << 6;
    int quad = lane >> 4, lrow = lane & 15;
    const float* z0p = z0 + p * D;
    u16* out = Zbuf + ((size_t)p * NB + b) * 512 * D;
    #pragma unroll
    for (int i = 0; i < 4; ++i)
        #pragma unroll
        for (int j = 0; j < 4; ++j) {
            int brow = r0 + wm + i * 16 + quad * 4;
            int col = c0 + wn + j * 16 + lrow;
            float zb = z0p[col];
            #pragma unroll
            for (int r = 0; r < 4; ++r)
                out[(size_t)(brow + r) * D + col] = f2b(acc[i][j][r] + zb);
        }
}

// kSsup: S[l][m] = (Z0[l].xb[m] + t[l]) * SCALE
__global__ __launch_bounds__(256) void kSsup_mfma(const u16* __restrict__ Zbuf,
        const u16* __restrict__ xb, const float* __restrict__ tbuf,
        const int* __restrict__ sepArr, u16* __restrict__ ssup) {
    __shared__ __align__(16) u16 As[128 * 32];
    __shared__ __align__(16) u16 Bs[128 * 32];
    int b = blockIdx.z;
    int sep = sepArr[b];
    int l0 = blockIdx.y * 128;
    if (l0 >= sep) return;
    int m0 = blockIdx.x * 128;
    if (m0 + 127 <= sep) return;
    float4v acc[4][4];
    gemm_core128(Zbuf + (size_t)b * 512 * D, D, l0,
                 xb + (size_t)b * L * D, D, m0, D, As, Bs, acc);
    int lane = threadIdx.x & 63, wave = threadIdx.x >> 6;
    int wm = (wave >> 1) << 6, wn = (wave & 1) << 6;
    int quad = lane >> 4, lrow = lane & 15;
    const float* tp = tbuf + (size_t)b * 512;   // p=0
    u16* out = ssup + (size_t)b * 512 * L;
    #pragma unroll
    for (int i = 0; i < 4; ++i)
        #pragma unroll
        for (int j = 0; j < 4; ++j) {
            int brow = l0 + wm + i * 16 + quad * 4;
            int col = m0 + wn + j * 16 + lrow;
            #pragma unroll
            for (int r = 0; r < 4; ++r)
                out[(size_t)(brow + r) * L + col] = f2b((acc[i][j][r] + tp[brow + r]) * SCALE);
        }
}

// kScmb: S[l][m] = (Zr.x + tr)*SCALE + tanh((Zc.x + tc)*SCALE), BM=64
__global__ __launch_bounds__(256) void kScmb_mfma(const u16* __restrict__ Zbuf,
        const u16* __restrict__ xb, const float* __restrict__ tbuf,
        const int* __restrict__ sepArr, u16* __restrict__ scmb) {
    __shared__ __align__(16) u16 Ar[64 * 32];
    __shared__ __align__(16) u16 Ac[64 * 32];
    __shared__ __align__(16) u16 Bs[128 * 32];
    int b = blockIdx.z;
    int sep = sepArr[b];
    int l0 = blockIdx.y * 64;
    if (l0 >= sep) return;
    int m0 = blockIdx.x * 128;
    if (m0 + 127 <= sep) return;
    const u16* Zr = Zbuf + ((size_t)2 * NB + b) * 512 * D;
    const u16* Zc = Zbuf + ((size_t)1 * NB + b) * 512 * D;
    const u16* X = xb + (size_t)b * L * D;
    int tid = threadIdx.x, lane = tid & 63, wave = tid >> 6;
    int wm = (wave >> 1) << 5, wn = (wave & 1) << 6;
    int quad = lane >> 4, lrow = lane & 15;
    float4v ar_[2][4], ac_[2][4];
    #pragma unroll
    for (int i = 0; i < 2; ++i)
        #pragma unroll
        for (int j = 0; j < 4; ++j) { ar_[i][j] = (float4v){0.f,0.f,0.f,0.f}; ac_[i][j] = (float4v){0.f,0.f,0.f,0.f}; }
    for (int k0 = 0; k0 < D; k0 += 32) {
        __syncthreads();
        stage64_async(Zr, D, l0, k0, Ar, tid);
        stage64_async(Zc, D, l0, k0, Ac, tid);
        stage128_async(X, D, m0, k0, Bs, tid);
        __syncthreads();
        short8 fr[2], fc[2], fb[4];
        #pragma unroll
        for (int i = 0; i < 2; ++i) {
            fr[i] = *(const short8*)&Ar[(wm + i * 16 + lrow) * 32 + quad * 8];
            fc[i] = *(const short8*)&Ac[(wm + i * 16 + lrow) * 32 + quad * 8];
        }
        #pragma unroll
        for (int j = 0; j < 4; ++j) fb[j] = *(const short8*)&Bs[(wn + j * 16 + lrow) * 32 + quad * 8];
        #pragma unroll
        for (int i = 0; i < 2; ++i)
            #pragma unroll
            for (int j = 0; j < 4; ++j) {
                ar_[i][j] = MFMA_BF16(fr[i], fb[j], ar_[i][j], 0, 0, 0);
                ac_[i][j] = MFMA_BF16(fc[i], fb[j], ac_[i][j], 0, 0, 0);
            }
    }
    const float* tr = tbuf + ((size_t)2 * NB + b) * 512;
    const float* tc = tbuf + ((size_t)1 * NB + b) * 512;
    u16* out = scmb + (size_t)b * 512 * L;
    #pragma unroll
    for (int i = 0; i < 2; ++i)
        #pragma unroll
        for (int j = 0; j < 4; ++j) {
            int brow = l0 + wm + i * 16 + quad * 4;
            int col = m0 + wn + j * 16 + lrow;
            #pragma unroll
            for (int r = 0; r < 4; ++r) {
                float vv = (ar_[i][j][r] + tr[brow + r]) * SCALE
                         + tanhf((ac_[i][j][r] + tc[brow + r]) * SCALE);
                out[(size_t)(brow + r) * L + col] = f2b(vv);
            }
        }
}

// ---------------- K2b: per-row masked softmax, write P = g*softmax in place ----------------
__global__ __launch_bounds__(256) void k2b(u16* __restrict__ ssup,
        u16* __restrict__ scmb, const int* __restrict__ ids,
        const int* __restrict__ padp, const int* __restrict__ sepArr,
        const float* __restrict__ gate, const int* __restrict__ flag) {
    int b = blockIdx.y, l = blockIdx.x;
    int sep = sepArr[b];
    if (l >= sep) return;
    float g = gate[b * L + l];
    int is64 = flag[1];
    int pad = padp[0];
    int tid = threadIdx.x;
    __shared__ float red[256];
    float s0[4], s1[4];
    u16* rs = ssup + ((size_t)b * 512 + l) * L;
    u16* rc = scmb + ((size_t)b * 512 + l) * L;
    float mx0 = -3.4e38f, mx1 = -3.4e38f;
    for (int u = 0; u < 4; ++u) {
        int m = tid + u * 256;
        bool ok = (m > sep) && (ldid(ids, (size_t)b * L + m, is64) != pad);
        s0[u] = ok ? b2f(rs[m]) : NEGV;
        s1[u] = ok ? b2f(rc[m]) : NEGV;
        mx0 = fmaxf(mx0, s0[u]); mx1 = fmaxf(mx1, s1[u]);
    }
    red[tid] = mx0; __syncthreads();
    for (int s = 128; s > 0; s >>= 1) { if (tid < s) red[tid] = fmaxf(red[tid], red[tid + s]); __syncthreads(); }
    mx0 = red[0]; __syncthreads();
    red[tid] = mx1; __syncthreads();
    for (int s = 128; s > 0; s >>= 1) { if (tid < s) red[tid] = fmaxf(red[tid], red[tid + s]); __syncthreads(); }
    mx1 = red[0]; __syncthreads();
    float e0s = 0.f, e1s = 0.f;
    for (int u = 0; u < 4; ++u) {
        s0[u] = expf(s0[u] - mx0); e0s += s0[u];
        s1[u] = expf(s1[u] - mx1); e1s += s1[u];
    }
    red[tid] = e0s; __syncthreads();
    for (int s = 128; s > 0; s >>= 1) { if (tid < s) red[tid] += red[tid + s]; __syncthreads(); }
    float d0 = fmaxf(red[0], 1e-30f); __syncthreads();
    red[tid] = e1s; __syncthreads();
    for (int s = 128; s > 0; s >>= 1) { if (tid < s) red[tid] += red[tid + s]; __syncthreads(); }
    float d1 = fmaxf(red[0], 1e-30f);
    float i0 = g / d0, i1 = g / d1;
    for (int u = 0; u < 4; ++u) {
        int m = tid + u * 256;
        rs[m] = f2b(s0[u] * i0);
        rc[m] = f2b(s1[u] * i1);
    }
}

// ---------------- kcol: csup[m] = sum_{l<sep} P0[l][m]; crep likewise ----------------
__global__ __launch_bounds__(256) void kcol(const u16* __restrict__ ssup,
        const u16* __restrict__ scmb, const int* __restrict__ sepArr,
        float* __restrict__ csup, float* __restrict__ crep) {
    __shared__ float r0s[256], r1s[256];
    int b = blockIdx.y, sep = sepArr[b];
    int tid = threadIdx.x;
    int m = blockIdx.x * 64 + (tid & 63);
    int q = tid >> 6;
    const u16* P0 = ssup + (size_t)b * 512 * L;
    const u16* P1 = scmb + (size_t)b * 512 * L;
    float s0 = 0.f, s1 = 0.f;
    for (int l = q; l < sep; l += 4) {
        s0 += b2f(P0[(size_t)l * L + m]);
        s1 += b2f(P1[(size_t)l * L + m]);
    }
    r0s[tid] = s0; r1s[tid] = s1; __syncthreads();
    if (q == 0) {
        s0 = r0s[tid] + r0s[tid + 64] + r0s[tid + 128] + r0s[tid + 192];
        s1 = r1s[tid] + r1s[tid + 64] + r1s[tid + 128] + r1s[tid + 192];
        csup[b * L + m] = s0; crep[b * L + m] = s1;
    }
}

// ---------------- K3: af/w_rep/w_sup weighted sums over x (32 rows/block) ----------------
template<int F32> __device__ void k3_body(const void* x, const float* gate,
        const float* csup, const float* crep, float* af, float* wrep, float* wsup) {
    int b = blockIdx.y, c = blockIdx.x;
    int tid = threadIdx.x;
    float a0 = 0.f, a1 = 0.f, a2 = 0.f;
    float r0 = 0.f, r1 = 0.f, r2 = 0.f;
    float q0 = 0.f, q1 = 0.f, q2 = 0.f;
    for (int mm = 0; mm < 32; ++mm) {
        int m = c * 32 + mm;
        float wg = gate[b * L + m], wr = crep[b * L + m], wq = csup[b * L + m];
        if (wg == 0.f && wr == 0.f && wq == 0.f) continue;
        size_t base = ((size_t)b * L + m) * D;
        float x0 = ld1<F32>(x, base + tid);
        float x1 = ld1<F32>(x, base + tid + 256);
        float x2 = ld1<F32>(x, base + tid + 512);
        a0 += wg * x0; a1 += wg * x1; a2 += wg * x2;
        r0 += wr * x0; r1 += wr * x1; r2 += wr * x2;
        q0 += wq * x0; q1 += wq * x1; q2 += wq * x2;
    }
    atomicAdd(&af[b * D + tid], a0); atomicAdd(&af[b * D + tid + 256], a1); atomicAdd(&af[b * D + tid + 512], a2);
    atomicAdd(&wrep[b * D + tid], r0); atomicAdd(&wrep[b * D + tid + 256], r1); atomicAdd(&wrep[b * D + tid + 512], r2);
    atomicAdd(&wsup[b * D + tid], q0); atomicAdd(&wsup[b * D + tid + 256], q1); atomicAdd(&wsup[b * D + tid + 512], q2);
}
__global__ __launch_bounds__(256) void k3(const void* x, const float* gate,
        const float* csup, const float* crep, float* af, float* wrep, float* wsup,
        const int* flag) {
    if (flag[0]) k3_body<1>(x, gate, csup, crep, af, wrep, wsup);
    else         k3_body<0>(x, gate, csup, crep, af, wrep, wsup);
}

// ---------------- kh1: hacc += fused @ Wf1 (split-K) ----------------
template<int F32> __device__ void kh1_body(const float* af, const float* wrep,
        const float* wsup, const void* Wf1, float* hacc, float* fs) {
    int tid = threadIdx.x;
    int c0 = blockIdx.x * 128, k0 = blockIdx.y * 144;
    for (int e = tid; e < 8 * 144; e += 256) {
        int b = e / 144, kk = e - b * 144;
        int k = k0 + kk;
        float v = (k < D) ? af[b * D + k] : (k < 2 * D) ? wrep[b * D + k - D]
                                                        : wsup[b * D + k - 2 * D];
        fs[b * 144 + kk] = v;
    }
    __syncthreads();
    int col = c0 + (tid & 127);
    int kg = tid >> 7;
    float acc[NB];
    #pragma unroll
    for (int b = 0; b < NB; ++b) acc[b] = 0.f;
    #pragma unroll 4
    for (int r = 0; r < 72; ++r) {
        int kk = kg * 72 + r;
        float w = ld1<F32>(Wf1, (size_t)(k0 + kk) * D + col);
        #pragma unroll
        for (int b = 0; b < NB; ++b) acc[b] += fs[b * 144 + kk] * w;
    }
    #pragma unroll
    for (int b = 0; b < NB; ++b) atomicAdd(&hacc[b * D + col], acc[b]);
}
__global__ __launch_bounds__(256) void kh1(const float* af, const float* wrep,
        const float* wsup, const void* Wf1, float* hacc, const int* flag) {
    __shared__ float fs[8 * 144];
    if (flag[0]) kh1_body<1>(af, wrep, wsup, Wf1, hacc, fs);
    else         kh1_body<0>(af, wrep, wsup, Wf1, hacc, fs);
}

// ---------------- kh2: oacc += relu(hacc+bf1) @ Wf2 (split-K) ----------------
template<int F32> __device__ void kh2_body(const float* hacc, const void* bf1,
        const void* Wf2, float* oacc, float* hsl) {
    int tid = threadIdx.x;
    int c0 = blockIdx.x * 128, k0 = blockIdx.y * 96;
    for (int e = tid; e < 8 * 96; e += 256) {
        int b = e / 96, kk = e - b * 96;
        int k = k0 + kk;
        hsl[b * 96 + kk] = fmaxf(hacc[b * D + k] + ld1<F32>(bf1, k), 0.f);
    }
    __syncthreads();
    int col = c0 + (tid & 127);
    int kg = tid >> 7;
    float acc[NB];
    #pragma unroll
    for (int b = 0; b < NB; ++b) acc[b] = 0.f;
    #pragma unroll 4
    for (int r = 0; r < 48; ++r) {
        int kk = kg * 48 + r;
        float w = ld1<F32>(Wf2, (size_t)(k0 + kk) * D + col);
        #pragma unroll
        for (int b = 0; b < NB; ++b) acc[b] += hsl[b * 96 + kk] * w;
    }
    #pragma unroll
    for (int b = 0; b < NB; ++b) atomicAdd(&oacc[b * D + col], acc[b]);
}
__global__ __launch_bounds__(256) void kh2(const float* hacc, const void* bf1,
        const void* Wf2, float* oacc, const int* flag) {
    __shared__ float hsl[8 * 96];
    if (flag[0]) kh2_body<1>(hacc, bf1, Wf2, oacc, hsl);
    else         kh2_body<0>(hacc, bf1, Wf2, oacc, hsl);
}

// ---------------- kln: out = LN(oacc + bf2) * gamma + beta ----------------
template<int F32> __device__ void kln_body(const float* oacc, const void* bf2,
        const void* gamma, const void* beta, void* out, float* red) {
    int b = blockIdx.x, tid = threadIdx.x;
    float o[3];
    #pragma unroll
    for (int u = 0; u < 3; ++u) {
        int i = tid + u * 256;
        o[u] = oacc[b * D + i] + ld1<F32>(bf2, i);
    }
    red[tid] = o[0] + o[1] + o[2]; __syncthreads();
    for (int s = 128; s > 0; s >>= 1) { if (tid < s) red[tid] += red[tid + s]; __syncthreads(); }
    float mu = red[0] / (float)D; __syncthreads();
    float vs = 0.f;
    #pragma unroll
    for (int u = 0; u < 3; ++u) vs += (o[u] - mu) * (o[u] - mu);
    red[tid] = vs; __syncthreads();
    for (int s = 128; s > 0; s >>= 1) { if (tid < s) red[tid] += red[tid + s]; __syncthreads(); }
    float var = red[0] / (float)D;
    float rstd = 1.0f / sqrtf(var + 1e-5f);
    #pragma unroll
    for (int u = 0; u < 3; ++u) {
        int i = tid + u * 256;
        float v = (o[u] - mu) * rstd * ld1<F32>(gamma, i) + ld1<F32>(beta, i);
        if (F32) ((float*)out)[b * D + i] = v;
        else     ((u16*)out)[b * D + i] = f2b(v);
    }
}
__global__ __launch_bounds__(256) void kln(const float* oacc, const void* bf2,
        const void* gamma, const void* beta, void* out, const int* flag) {
    __shared__ float red[256];
    if (flag[0]) kln_body<1>(oacc, bf2, gamma, beta, out, red);
    else         kln_body<0>(oacc, bf2, gamma, beta, out, red);
}

extern "C" void kernel_launch(void* const* d_in, const int* in_sizes, int n_in,
                              void* d_out, int out_size, void* d_ws, size_t ws_size,
                              hipStream_t stream) {
    const void* x    = d_in[0];
    const int* ids   = (const int*)d_in[1];
    const int* padp  = (const int*)d_in[2];
    const void* Wa   = d_in[3];
    const void* ba   = d_in[4];
    PP pp;
    pp.W[0] = d_in[5];  pp.b[0] = d_in[6];    // qs
    pp.W[1] = d_in[7];  pp.b[1] = d_in[8];    // ks
    pp.W[2] = d_in[9];  pp.b[2] = d_in[10];   // qc
    pp.W[3] = d_in[11]; pp.b[3] = d_in[12];   // kc
    pp.W[4] = d_in[13]; pp.b[4] = d_in[14];   // qr
    pp.W[5] = d_in[15]; pp.b[5] = d_in[16];   // kr
    const void* Wf1 = d_in[17]; const void* bf1 = d_in[18];
    const void* Wf2 = d_in[19]; const void* bf2 = d_in[20];
    const void* gamma = d_in[21]; const void* beta = d_in[22];

    char* ws = (char*)d_ws;
    int*   flag   = (int*)(ws + WS_FLAG);
    int*   sepArr = (int*)(ws + WS_SEP);
    float* c0   = (float*)(ws + WS_C0);
    float* z0   = (float*)(ws + WS_Z0);
    float* w1   = (float*)(ws + WS_W1);
    float* gate = (float*)(ws + WS_GATE);
    float* csup = (float*)(ws + WS_CSUP);
    float* crep = (float*)(ws + WS_CREP);
    float* af   = (float*)(ws + WS_AF);
    float* wrep = (float*)(ws + WS_WREP);
    float* wsup = (float*)(ws + WS_WSUP);
    float* hacc = (float*)(ws + WS_HACC);
    float* oacc = (float*)(ws + WS_OACC);
    float* alog = (float*)(ws + WS_ALOG);
    float* tbuf = (float*)(ws + WS_T);
    u16* xb   = (u16*)(ws + WS_XB);
    u16* Zbuf = (u16*)(ws + WS_Z);
    u16* Wb   = (u16*)(ws + WS_WB);
    u16* Mt   = (u16*)(ws + WS_M);
    u16* ssup = (u16*)(ws + WS_SSUP);
    u16* scmb = (u16*)(ws + WS_SCMB);

    kdetect<<<dim3(1), dim3(128), 0, stream>>>(x, ids, flag);
    kconv<<<dim3(4800), dim3(256), 0, stream>>>(x, pp, xb, Wb, flag);
    kbias_row<<<dim3(12, 6), dim3(256), 0, stream>>>(pp, z0, w1, flag);
    kc0<<<dim3(3), dim3(256), 0, stream>>>(pp, c0, flag);
    kdots<<<dim3(NB * L / 32), dim3(256), 0, stream>>>(x, Wa, ba, w1, c0, alog, tbuf, flag);
    k0b<<<dim3(NB), dim3(256), 0, stream>>>(ids, padp, alog, gate, sepArr,
                                            af, wrep, wsup, hacc, oacc, flag);
    kM_mfma<<<dim3(6, 6, 3), dim3(256), 0, stream>>>(Wb, Mt);
    kZ_mfma<<<dim3(6, 4, 24), dim3(256), 0, stream>>>(xb, Mt, z0, Zbuf, sepArr);
    kSsup_mfma<<<dim3(8, 4, NB), dim3(256), 0, stream>>>(Zbuf, xb, tbuf, sepArr, ssup);
    kScmb_mfma<<<dim3(8, 8, NB), dim3(256), 0, stream>>>(Zbuf, xb, tbuf, sepArr, scmb);
    k2b<<<dim3(512, NB), dim3(256), 0, stream>>>(ssup, scmb, ids, padp, sepArr, gate, flag);
    kcol<<<dim3(16, NB), dim3(256), 0, stream>>>(ssup, scmb, sepArr, csup, crep);
    k3<<<dim3(32, NB), dim3(256), 0, stream>>>(x, gate, csup, crep, af, wrep, wsup, flag);
    kh1<<<dim3(6, 16), dim3(256), 0, stream>>>(af, wrep, wsup, Wf1, hacc, flag);
    kh2<<<dim3(6, 8), dim3(256), 0, stream>>>(hacc, bf1, Wf2, oacc, flag);
    kln<<<dim3(NB), dim3(256), 0, stream>>>(oacc, bf2, gamma, beta, d_out, flag);
}

// Round 6
// 313.871 us; speedup vs baseline: 4.1012x; 1.0564x over previous
//
#include <hip/hip_runtime.h>
#include <math.h>

#define L 1024
#define NB 8
#define D 768
#define NEGV (-9.0e15f)
#define SCALE 0.036084391824351615f  // 1/sqrt(768)

typedef unsigned short u16;
typedef __attribute__((ext_vector_type(8))) short short8;
typedef __attribute__((ext_vector_type(4))) float float4v;
#define MFMA_BF16 __builtin_amdgcn_mfma_f32_16x16x32_bf16

__device__ __forceinline__ float b2f(u16 u) {
    union { unsigned int i; float f; } v; v.i = ((unsigned int)u) << 16; return v.f;
}
__device__ __forceinline__ u16 f2b(float f) {
    union { float fv; unsigned int i; } v; v.fv = f;
    unsigned int x = v.i;
    x += 0x7fffu + ((x >> 16) & 1u);   // RNE
    return (u16)(x >> 16);
}

template<int F32>
__device__ __forceinline__ float4 ld4(const void* p, size_t idx) {
    if (F32) return *(const float4*)((const float*)p + idx);
    ushort4 v = *(const ushort4*)((const u16*)p + idx);
    return make_float4(b2f(v.x), b2f(v.y), b2f(v.z), b2f(v.w));
}
template<int F32>
__device__ __forceinline__ float ld1(const void* p, size_t idx) {
    if (F32) return ((const float*)p)[idx];
    return b2f(((const u16*)p)[idx]);
}
__device__ __forceinline__ int ldid(const int* p, size_t idx, int is64) {
    return is64 ? p[idx * 2] : p[idx];
}

// ---------------- workspace layout (bytes) ----------------
#define WS_FLAG  ((size_t)0)
#define WS_SEP   ((size_t)64)
#define WS_C0    ((size_t)128)
#define WS_Z0    ((size_t)192)
#define WS_W1    ((size_t)9472)
#define WS_GATE  ((size_t)18752)
#define WS_CSUP  ((size_t)51520)
#define WS_CREP  ((size_t)84288)
#define WS_AF    ((size_t)117056)
#define WS_WREP  ((size_t)141632)
#define WS_WSUP  ((size_t)166208)
#define WS_HACC  ((size_t)190784)
#define WS_ALOG  ((size_t)215360)
#define WS_T     ((size_t)248128)     // 3*NB*512 f32 -> ends 297280
#define WS_OACC  ((size_t)303104)
#define WS_XB    ((size_t)524288)     // NB*L*D bf16 -> 13107200
#define WS_Z     ((size_t)13107200)   // 3*NB*512*D bf16 -> 31981568
#define WS_SSUP  ((size_t)31981568)   // NB*512*L bf16 -> 40370176
#define WS_WB    WS_SSUP              // 6*D*D bf16 (dead before kSsup writes)
#define WS_SCMB  ((size_t)40370176)   // NB*512*L bf16 -> 48758784
#define WS_M     WS_SCMB              // 3*D*D bf16 (dead before kScmb writes)

struct PP { const void* W[6]; const void* b[6]; };

// ---------------- detect dtypes ----------------
__global__ __launch_bounds__(128) void kdetect(const void* x, const void* ids, int* flag) {
    __shared__ int cnt[2];
    int tid = threadIdx.x;
    if (tid == 0) { cnt[0] = 0; cnt[1] = 0; }
    __syncthreads();
    if (tid < 64) {
        u16 u = ((const u16*)x)[tid * 2];
        int e = (u >> 7) & 0xFF;
        if (e >= 100 && e <= 140) atomicAdd(&cnt[0], 1);
    } else {
        int v = ((const int*)ids)[(tid - 64) * 2 + 1];
        if (v != 0) atomicAdd(&cnt[1], 1);
    }
    __syncthreads();
    if (tid == 0) {
        flag[0] = (cnt[0] < 32) ? 1 : 0;   // 1 => floats are f32
        flag[1] = (cnt[1] == 0) ? 1 : 0;   // 1 => ids are int64
    }
}

// ---------------- kbias_row: z0 = Wk@bq / w1 = Wq@bk / (y==6) c0 = bq.bk ----------------
template<int F32> __device__ void kbias_body(const void* W, const void* vec,
        float* out, float* vs) {
    int tid = threadIdx.x;
    for (int i = tid; i < D; i += 256) vs[i] = ld1<F32>(vec, i);
    __syncthreads();
    int row = blockIdx.x * 64 + (tid >> 2);
    int sub = tid & 3;
    float acc = 0.f;
    for (int i = 0; i < 48; ++i) {
        int k = i * 16 + sub * 4;
        float4 wv = ld4<F32>(W, (size_t)row * D + k);
        acc += wv.x * vs[k] + wv.y * vs[k + 1] + wv.z * vs[k + 2] + wv.w * vs[k + 3];
    }
    acc += __shfl_xor(acc, 1);
    acc += __shfl_xor(acc, 2);
    if (sub == 0) out[row] = acc;
}
template<int F32> __device__ void kc0_body(const void* bq, const void* bk,
        float* c0, int p, float* red) {
    int tid = threadIdx.x;
    float s = 0.f;
    for (int i = tid; i < D; i += 256) s += ld1<F32>(bq, i) * ld1<F32>(bk, i);
    red[tid] = s; __syncthreads();
    for (int st = 128; st > 0; st >>= 1) { if (tid < st) red[tid] += red[tid + st]; __syncthreads(); }
    if (tid == 0) c0[p] = red[0];
}
__global__ __launch_bounds__(256) void kbias_row(PP pp, float* z0, float* w1,
        float* c0, const int* flag) {
    __shared__ float vs[D];
    __shared__ float red[256];
    int y = blockIdx.y;
    if (y == 6) {
        int p = blockIdx.x;
        if (p >= 3) return;
        if (flag[0]) kc0_body<1>(pp.b[2 * p], pp.b[2 * p + 1], c0, p, red);
        else         kc0_body<0>(pp.b[2 * p], pp.b[2 * p + 1], c0, p, red);
        return;
    }
    int p = y >> 1, which = y & 1;
    const void* W   = which ? pp.W[2 * p]     : pp.W[2 * p + 1];
    const void* vec = which ? pp.b[2 * p + 1] : pp.b[2 * p];
    float* out = (which ? w1 : z0) + p * D;
    if (flag[0]) kbias_body<1>(W, vec, out, vs);
    else         kbias_body<0>(W, vec, out, vs);
}

// ---------------- kx: fused x->bf16 conversion + 4 row-dot products + W->bf16 ----------------
// blocks [0,256): 32 x-rows each — convert to xb AND compute alog/t dots from same loads.
// blocks [256,1984): weight conversion, 6 matrices x 288 blocks.
template<int F32> __device__ void kx_body(const void* x, const void* Wa,
        const void* ba, const float* w1, const float* c0, u16* xb, float* alog,
        float* tbuf, float* ws4) {
    int tid = threadIdx.x;
    for (int i = tid; i < D; i += 256) {
        ws4[i]         = ld1<F32>(Wa, i);
        ws4[D + i]     = w1[i];
        ws4[2 * D + i] = w1[D + i];
        ws4[3 * D + i] = w1[2 * D + i];
    }
    __syncthreads();
    int row = blockIdx.x * 32 + (tid >> 3);   // global row in [0, NB*L)
    int sub = tid & 7;
    float a0 = 0.f, a1 = 0.f, a2 = 0.f, a3 = 0.f;
    for (int i = 0; i < 24; ++i) {
        int k = i * 32 + sub * 4;
        float4 xv = ld4<F32>(x, (size_t)row * D + k);
        ushort4 o;
        o.x = f2b(xv.x); o.y = f2b(xv.y); o.z = f2b(xv.z); o.w = f2b(xv.w);
        *(ushort4*)(xb + (size_t)row * D + k) = o;
        a0 += xv.x * ws4[k] + xv.y * ws4[k + 1] + xv.z * ws4[k + 2] + xv.w * ws4[k + 3];
        a1 += xv.x * ws4[D + k] + xv.y * ws4[D + k + 1] + xv.z * ws4[D + k + 2] + xv.w * ws4[D + k + 3];
        a2 += xv.x * ws4[2 * D + k] + xv.y * ws4[2 * D + k + 1] + xv.z * ws4[2 * D + k + 2] + xv.w * ws4[2 * D + k + 3];
        a3 += xv.x * ws4[3 * D + k] + xv.y * ws4[3 * D + k + 1] + xv.z * ws4[3 * D + k + 2] + xv.w * ws4[3 * D + k + 3];
    }
    #pragma unroll
    for (int d = 1; d < 8; d <<= 1) {
        a0 += __shfl_xor(a0, d); a1 += __shfl_xor(a1, d);
        a2 += __shfl_xor(a2, d); a3 += __shfl_xor(a3, d);
    }
    int b = row >> 10, l = row & 1023;
    if (sub == 0) alog[row] = a0 + ld1<F32>(ba, 0);
    else if (sub == 1 && l < 512) tbuf[((size_t)0 * NB + b) * 512 + l] = a1 + c0[0];
    else if (sub == 2 && l < 512) tbuf[((size_t)1 * NB + b) * 512 + l] = a2 + c0[1];
    else if (sub == 3 && l < 512) tbuf[((size_t)2 * NB + b) * 512 + l] = a3 + c0[2];
}
__global__ __launch_bounds__(256) void kx(const void* x, PP pp, const void* Wa,
        const void* ba, const float* w1, const float* c0, u16* xb, u16* Wb,
        float* alog, float* tbuf, const int* flag) {
    __shared__ float ws4[4 * D];
    int bid = blockIdx.x;
    if (bid < 256) {
        if (flag[0]) kx_body<1>(x, Wa, ba, w1, c0, xb, alog, tbuf, ws4);
        else         kx_body<0>(x, Wa, ba, w1, c0, xb, alog, tbuf, ws4);
        return;
    }
    int t = (bid - 256) / 288, inner = (bid - 256) % 288;
    const void* src = pp.W[t];
    u16* dst = Wb + (size_t)t * D * D;
    size_t base = ((size_t)inner * 256 + threadIdx.x) * 8;
    if (flag[0]) {
        float4 a = *(const float4*)((const float*)src + base);
        float4 b = *(const float4*)((const float*)src + base + 4);
        uint4 o; u16* po = (u16*)&o;
        po[0] = f2b(a.x); po[1] = f2b(a.y); po[2] = f2b(a.z); po[3] = f2b(a.w);
        po[4] = f2b(b.x); po[5] = f2b(b.y); po[6] = f2b(b.z); po[7] = f2b(b.w);
        *(uint4*)(dst + base) = o;
    } else {
        *(uint4*)(dst + base) = *(const uint4*)((const u16*)src + base);
    }
}

// ---------------- K0b: sep, gate softmax, zero accumulators ----------------
__global__ __launch_bounds__(256) void k0b(const int* __restrict__ ids,
        const int* __restrict__ padp, const float* __restrict__ alog,
        float* __restrict__ gate, int* __restrict__ sepArr,
        float* __restrict__ af, float* __restrict__ wrep, float* __restrict__ wsup,
        float* __restrict__ hacc, float* __restrict__ oacc,
        float* __restrict__ csup, float* __restrict__ crep,
        const int* __restrict__ flag) {
    __shared__ float red[256];
    __shared__ int sepSh;
    int is64 = flag[1];
    int b = blockIdx.x, tid = threadIdx.x;
    int pad = padp[0];
    int cnt = 0;
    for (int l = tid; l < L; l += 256) cnt += (ldid(ids, (size_t)b * L + l, is64) != pad) ? 1 : 0;
    red[tid] = (float)cnt; __syncthreads();
    for (int s = 128; s > 0; s >>= 1) { if (tid < s) red[tid] += red[tid + s]; __syncthreads(); }
    if (tid == 0) {
        int vl = (int)red[0];
        int sep = vl / 2; if (sep < 1) sep = 1; if (sep > L - 2) sep = L - 2;
        sepSh = sep; sepArr[b] = sep;
    }
    __syncthreads();
    int sep = sepSh;
    float lv[4]; int lidx[4];
    float mx = -3.4e38f;
    for (int u = 0; u < 4; ++u) {
        int l = tid + u * 256; lidx[u] = l;
        bool fm = (l < sep) && (ldid(ids, (size_t)b * L + l, is64) != pad);
        float v = fm ? alog[b * L + l] : NEGV;
        lv[u] = v; mx = fmaxf(mx, v);
    }
    red[tid] = mx; __syncthreads();
    for (int s = 128; s > 0; s >>= 1) { if (tid < s) red[tid] = fmaxf(red[tid], red[tid + s]); __syncthreads(); }
    mx = red[0]; __syncthreads();
    float se = 0.f;
    for (int u = 0; u < 4; ++u) { lv[u] = expf(lv[u] - mx); se += lv[u]; }
    red[tid] = se; __syncthreads();
    for (int s = 128; s > 0; s >>= 1) { if (tid < s) red[tid] += red[tid + s]; __syncthreads(); }
    float den = fmaxf(red[0], 1e-30f); __syncthreads();
    float gs = 0.f; float gv[4];
    for (int u = 0; u < 4; ++u) {
        int l = lidx[u];
        bool fm = (l < sep) && (ldid(ids, (size_t)b * L + l, is64) != pad);
        float p = lv[u] / den;
        gv[u] = fm ? p : 0.f;
        gs += gv[u];
    }
    red[tid] = gs; __syncthreads();
    for (int s = 128; s > 0; s >>= 1) { if (tid < s) red[tid] += red[tid + s]; __syncthreads(); }
    gs = red[0];
    float inv = 1.f / fmaxf(gs, 1e-8f);
    for (int u = 0; u < 4; ++u) gate[b * L + lidx[u]] = gv[u] * inv;
    for (int l = tid; l < L; l += 256) { csup[b * L + l] = 0.f; crep[b * L + l] = 0.f; }
    for (int i = tid; i < D; i += 256) {
        af[b * D + i] = 0.f; wrep[b * D + i] = 0.f; wsup[b * D + i] = 0.f;
        hacc[b * D + i] = 0.f; oacc[b * D + i] = 0.f;
    }
}

// ================= MFMA GEMM (A . B^T), async global->LDS staging =================
__device__ __forceinline__ void stage128_async(const u16* __restrict__ G, size_t ld,
        int r0, int k0, u16* S, int tid) {
    int rowa = tid >> 2, koa = (tid & 3) << 3;
    int wave = tid >> 6;
    const u16* g1 = &G[(size_t)(r0 + rowa) * ld + k0 + koa];
    const u16* g2 = &G[(size_t)(r0 + rowa + 64) * ld + k0 + koa];
    __builtin_amdgcn_global_load_lds((__attribute__((address_space(1))) void*)(u16*)g1,
        (__attribute__((address_space(3))) void*)(S + wave * 512), 16, 0, 0);
    __builtin_amdgcn_global_load_lds((__attribute__((address_space(1))) void*)(u16*)g2,
        (__attribute__((address_space(3))) void*)(S + 2048 + wave * 512), 16, 0, 0);
}
__device__ __forceinline__ void stage64_async(const u16* __restrict__ G, size_t ld,
        int r0, int k0, u16* S, int tid) {
    int rowa = tid >> 2, koa = (tid & 3) << 3;
    int wave = tid >> 6;
    const u16* g = &G[(size_t)(r0 + rowa) * ld + k0 + koa];
    __builtin_amdgcn_global_load_lds((__attribute__((address_space(1))) void*)(u16*)g,
        (__attribute__((address_space(3))) void*)(S + wave * 512), 16, 0, 0);
}

__device__ __forceinline__ void gemm_core128(const u16* __restrict__ A, size_t lda, int r0,
        const u16* __restrict__ B, size_t ldb, int c0, int K,
        u16* As, u16* Bs, float4v acc[4][4]) {
    int tid = threadIdx.x;
    int lane = tid & 63, wave = tid >> 6;
    int wm = (wave >> 1) << 6, wn = (wave & 1) << 6;
    int quad = lane >> 4, lrow = lane & 15;
    #pragma unroll
    for (int i = 0; i < 4; ++i)
        #pragma unroll
        for (int j = 0; j < 4; ++j) acc[i][j] = (float4v){0.f, 0.f, 0.f, 0.f};
    for (int k0 = 0; k0 < K; k0 += 32) {
        __syncthreads();
        stage128_async(A, lda, r0, k0, As, tid);
        stage128_async(B, ldb, c0, k0, Bs, tid);
        __syncthreads();
        short8 af[4], bf[4];
        #pragma unroll
        for (int i = 0; i < 4; ++i) af[i] = *(const short8*)&As[(wm + i * 16 + lrow) * 32 + quad * 8];
        #pragma unroll
        for (int j = 0; j < 4; ++j) bf[j] = *(const short8*)&Bs[(wn + j * 16 + lrow) * 32 + quad * 8];
        #pragma unroll
        for (int i = 0; i < 4; ++i)
            #pragma unroll
            for (int j = 0; j < 4; ++j)
                acc[i][j] = MFMA_BF16(af[i], bf[j], acc[i][j], 0, 0, 0);
    }
}

// kM: Mt[j][k'] = sum_c Wk[j][c] Wq[k'][c]
__global__ __launch_bounds__(256) void kM_mfma(const u16* __restrict__ Wb, u16* __restrict__ Mt) {
    __shared__ __align__(16) u16 As[128 * 32];
    __shared__ __align__(16) u16 Bs[128 * 32];
    int p = blockIdx.z;
    int r0 = blockIdx.y * 128, c0 = blockIdx.x * 128;
    float4v acc[4][4];
    gemm_core128(Wb + (size_t)(2 * p + 1) * D * D, D, r0,
                 Wb + (size_t)(2 * p) * D * D, D, c0, D, As, Bs, acc);
    int lane = threadIdx.x & 63, wave = threadIdx.x >> 6;
    int wm = (wave >> 1) << 6, wn = (wave & 1) << 6;
    int quad = lane >> 4, lrow = lane & 15;
    u16* out = Mt + (size_t)p * D * D;
    #pragma unroll
    for (int i = 0; i < 4; ++i)
        #pragma unroll
        for (int j = 0; j < 4; ++j) {
            int brow = r0 + wm + i * 16 + quad * 4;
            int col = c0 + wn + j * 16 + lrow;
            #pragma unroll
            for (int r = 0; r < 4; ++r)
                out[(size_t)(brow + r) * D + col] = f2b(acc[i][j][r]);
        }
}

// kZ: Z[l][j] = sum_k xb[l][k] Mt[j][k] + z0[j]
__global__ __launch_bounds__(256) void kZ_mfma(const u16* __restrict__ xb,
        const u16* __restrict__ Mt, const float* __restrict__ z0,
        u16* __restrict__ Zbuf, const int* __restrict__ sepArr) {
    __shared__ __align__(16) u16 As[128 * 32];
    __shared__ __align__(16) u16 Bs[128 * 32];
    int z = blockIdx.z;
    int p = z >> 3, b = z & 7;
    int sep = sepArr[b];
    int r0 = blockIdx.y * 128;
    if (r0 >= sep) return;
    int c0 = blockIdx.x * 128;
    float4v acc[4][4];
    gemm_core128(xb + (size_t)b * L * D, D, r0,
                 Mt + (size_t)p * D * D, D, c0, D, As, Bs, acc);
    int lane = threadIdx.x & 63, wave = threadIdx.x >> 6;
    int wm = (wave >> 1) << 6, wn = (wave & 1) << 6;
    int quad = lane >> 4, lrow = lane & 15;
    const float* z0p = z0 + p * D;
    u16* out = Zbuf + ((size_t)p * NB + b) * 512 * D;
    #pragma unroll
    for (int i = 0; i < 4; ++i)
        #pragma unroll
        for (int j = 0; j < 4; ++j) {
            int brow = r0 + wm + i * 16 + quad * 4;
            int col = c0 + wn + j * 16 + lrow;
            float zb = z0p[col];
            #pragma unroll
            for (int r = 0; r < 4; ++r)
                out[(size_t)(brow + r) * D + col] = f2b(acc[i][j][r] + zb);
        }
}

// kSsup: S[l][m] = (Z0[l].xb[m] + t[l]) * SCALE
__global__ __launch_bounds__(256) void kSsup_mfma(const u16* __restrict__ Zbuf,
        const u16* __restrict__ xb, const float* __restrict__ tbuf,
        const int* __restrict__ sepArr, u16* __restrict__ ssup) {
    __shared__ __align__(16) u16 As[128 * 32];
    __shared__ __align__(16) u16 Bs[128 * 32];
    int b = blockIdx.z;
    int sep = sepArr[b];
    int l0 = blockIdx.y * 128;
    if (l0 >= sep) return;
    int m0 = blockIdx.x * 128;
    if (m0 + 127 <= sep) return;
    float4v acc[4][4];
    gemm_core128(Zbuf + (size_t)b * 512 * D, D, l0,
                 xb + (size_t)b * L * D, D, m0, D, As, Bs, acc);
    int lane = threadIdx.x & 63, wave = threadIdx.x >> 6;
    int wm = (wave >> 1) << 6, wn = (wave & 1) << 6;
    int quad = lane >> 4, lrow = lane & 15;
    const float* tp = tbuf + (size_t)b * 512;   // p=0
    u16* out = ssup + (size_t)b * 512 * L;
    #pragma unroll
    for (int i = 0; i < 4; ++i)
        #pragma unroll
        for (int j = 0; j < 4; ++j) {
            int brow = l0 + wm + i * 16 + quad * 4;
            int col = m0 + wn + j * 16 + lrow;
            #pragma unroll
            for (int r = 0; r < 4; ++r)
                out[(size_t)(brow + r) * L + col] = f2b((acc[i][j][r] + tp[brow + r]) * SCALE);
        }
}

// kScmb: S[l][m] = (Zr.x + tr)*SCALE + tanh((Zc.x + tc)*SCALE), BM=64
__global__ __launch_bounds__(256) void kScmb_mfma(const u16* __restrict__ Zbuf,
        const u16* __restrict__ xb, const float* __restrict__ tbuf,
        const int* __restrict__ sepArr, u16* __restrict__ scmb) {
    __shared__ __align__(16) u16 Ar[64 * 32];
    __shared__ __align__(16) u16 Ac[64 * 32];
    __shared__ __align__(16) u16 Bs[128 * 32];
    int b = blockIdx.z;
    int sep = sepArr[b];
    int l0 = blockIdx.y * 64;
    if (l0 >= sep) return;
    int m0 = blockIdx.x * 128;
    if (m0 + 127 <= sep) return;
    const u16* Zr = Zbuf + ((size_t)2 * NB + b) * 512 * D;
    const u16* Zc = Zbuf + ((size_t)1 * NB + b) * 512 * D;
    const u16* X = xb + (size_t)b * L * D;
    int tid = threadIdx.x, lane = tid & 63, wave = tid >> 6;
    int wm = (wave >> 1) << 5, wn = (wave & 1) << 6;
    int quad = lane >> 4, lrow = lane & 15;
    float4v ar_[2][4], ac_[2][4];
    #pragma unroll
    for (int i = 0; i < 2; ++i)
        #pragma unroll
        for (int j = 0; j < 4; ++j) { ar_[i][j] = (float4v){0.f,0.f,0.f,0.f}; ac_[i][j] = (float4v){0.f,0.f,0.f,0.f}; }
    for (int k0 = 0; k0 < D; k0 += 32) {
        __syncthreads();
        stage64_async(Zr, D, l0, k0, Ar, tid);
        stage64_async(Zc, D, l0, k0, Ac, tid);
        stage128_async(X, D, m0, k0, Bs, tid);
        __syncthreads();
        short8 fr[2], fc[2], fb[4];
        #pragma unroll
        for (int i = 0; i < 2; ++i) {
            fr[i] = *(const short8*)&Ar[(wm + i * 16 + lrow) * 32 + quad * 8];
            fc[i] = *(const short8*)&Ac[(wm + i * 16 + lrow) * 32 + quad * 8];
        }
        #pragma unroll
        for (int j = 0; j < 4; ++j) fb[j] = *(const short8*)&Bs[(wn + j * 16 + lrow) * 32 + quad * 8];
        #pragma unroll
        for (int i = 0; i < 2; ++i)
            #pragma unroll
            for (int j = 0; j < 4; ++j) {
                ar_[i][j] = MFMA_BF16(fr[i], fb[j], ar_[i][j], 0, 0, 0);
                ac_[i][j] = MFMA_BF16(fc[i], fb[j], ac_[i][j], 0, 0, 0);
            }
    }
    const float* tr = tbuf + ((size_t)2 * NB + b) * 512;
    const float* tc = tbuf + ((size_t)1 * NB + b) * 512;
    u16* out = scmb + (size_t)b * 512 * L;
    #pragma unroll
    for (int i = 0; i < 2; ++i)
        #pragma unroll
        for (int j = 0; j < 4; ++j) {
            int brow = l0 + wm + i * 16 + quad * 4;
            int col = m0 + wn + j * 16 + lrow;
            #pragma unroll
            for (int r = 0; r < 4; ++r) {
                float vv = (ar_[i][j][r] + tr[brow + r]) * SCALE
                         + tanhf((ac_[i][j][r] + tc[brow + r]) * SCALE);
                out[(size_t)(brow + r) * L + col] = f2b(vv);
            }
        }
}

// ---------------- k2bc: fused per-row softmax + column-weight accumulation ----------------
// No P materialization: each wave owns rows, shuffle-reduces softmax, accumulates
// g*softmax into per-wave LDS column accumulators; one atomicAdd per column per block.
__global__ __launch_bounds__(256) void k2bc(const u16* __restrict__ ssup,
        const u16* __restrict__ scmb, const int* __restrict__ ids,
        const int* __restrict__ padp, const int* __restrict__ sepArr,
        const float* __restrict__ gate, float* __restrict__ csup,
        float* __restrict__ crep, const int* __restrict__ flag) {
    __shared__ float colacc[4][2][1024];   // [wave][mat][col] = 32 KB
    int b = blockIdx.y;
    int sep = sepArr[b];
    int l0 = blockIdx.x * 16;
    int tid = threadIdx.x, lane = tid & 63, w = tid >> 6;
    for (int i = tid; i < 4 * 2 * 1024; i += 256) ((float*)colacc)[i] = 0.f;
    __syncthreads();
    if (l0 < sep) {
        int is64 = flag[1];
        int pad = padp[0];
        unsigned int okmask = 0;
        #pragma unroll
        for (int u = 0; u < 16; ++u) {
            int m = u * 64 + lane;
            bool ok = (m > sep) && (ldid(ids, (size_t)b * L + m, is64) != pad);
            okmask |= (ok ? 1u : 0u) << u;
        }
        for (int t = 0; t < 4; ++t) {
            int l = l0 + w * 4 + t;
            if (l >= sep) continue;
            float g = gate[b * L + l];
            if (g == 0.f) continue;
            const u16* rs = ssup + ((size_t)b * 512 + l) * L;
            const u16* rc = scmb + ((size_t)b * 512 + l) * L;
            float s0[16], s1[16];
            float mx0 = -3.4e38f, mx1 = -3.4e38f;
            #pragma unroll
            for (int u = 0; u < 16; ++u) {
                int m = u * 64 + lane;
                bool ok = (okmask >> u) & 1u;
                s0[u] = ok ? b2f(rs[m]) : NEGV;
                s1[u] = ok ? b2f(rc[m]) : NEGV;
                mx0 = fmaxf(mx0, s0[u]); mx1 = fmaxf(mx1, s1[u]);
            }
            #pragma unroll
            for (int d = 1; d < 64; d <<= 1) {
                mx0 = fmaxf(mx0, __shfl_xor(mx0, d));
                mx1 = fmaxf(mx1, __shfl_xor(mx1, d));
            }
            float e0 = 0.f, e1 = 0.f;
            #pragma unroll
            for (int u = 0; u < 16; ++u) {
                s0[u] = expf(s0[u] - mx0); e0 += s0[u];
                s1[u] = expf(s1[u] - mx1); e1 += s1[u];
            }
            #pragma unroll
            for (int d = 1; d < 64; d <<= 1) {
                e0 += __shfl_xor(e0, d);
                e1 += __shfl_xor(e1, d);
            }
            float i0 = g / fmaxf(e0, 1e-30f), i1 = g / fmaxf(e1, 1e-30f);
            #pragma unroll
            for (int u = 0; u < 16; ++u) {
                int m = u * 64 + lane;
                colacc[w][0][m] += s0[u] * i0;
                colacc[w][1][m] += s1[u] * i1;
            }
        }
    }
    __syncthreads();
    for (int m = tid; m < 1024; m += 256) {
        float a0 = colacc[0][0][m] + colacc[1][0][m] + colacc[2][0][m] + colacc[3][0][m];
        float a1 = colacc[0][1][m] + colacc[1][1][m] + colacc[2][1][m] + colacc[3][1][m];
        if (a0 != 0.f) atomicAdd(&csup[b * L + m], a0);
        if (a1 != 0.f) atomicAdd(&crep[b * L + m], a1);
    }
}

// ---------------- K3: af/w_rep/w_sup weighted sums over x (16 rows/block) ----------------
template<int F32> __device__ void k3_body(const void* x, const float* gate,
        const float* csup, const float* crep, float* af, float* wrep, float* wsup) {
    int b = blockIdx.y, c = blockIdx.x;
    int tid = threadIdx.x;
    float a0 = 0.f, a1 = 0.f, a2 = 0.f;
    float r0 = 0.f, r1 = 0.f, r2 = 0.f;
    float q0 = 0.f, q1 = 0.f, q2 = 0.f;
    for (int mm = 0; mm < 16; ++mm) {
        int m = c * 16 + mm;
        float wg = gate[b * L + m], wr = crep[b * L + m], wq = csup[b * L + m];
        if (wg == 0.f && wr == 0.f && wq == 0.f) continue;
        size_t base = ((size_t)b * L + m) * D;
        float x0 = ld1<F32>(x, base + tid);
        float x1 = ld1<F32>(x, base + tid + 256);
        float x2 = ld1<F32>(x, base + tid + 512);
        a0 += wg * x0; a1 += wg * x1; a2 += wg * x2;
        r0 += wr * x0; r1 += wr * x1; r2 += wr * x2;
        q0 += wq * x0; q1 += wq * x1; q2 += wq * x2;
    }
    atomicAdd(&af[b * D + tid], a0); atomicAdd(&af[b * D + tid + 256], a1); atomicAdd(&af[b * D + tid + 512], a2);
    atomicAdd(&wrep[b * D + tid], r0); atomicAdd(&wrep[b * D + tid + 256], r1); atomicAdd(&wrep[b * D + tid + 512], r2);
    atomicAdd(&wsup[b * D + tid], q0); atomicAdd(&wsup[b * D + tid + 256], q1); atomicAdd(&wsup[b * D + tid + 512], q2);
}
__global__ __launch_bounds__(256) void k3(const void* x, const float* gate,
        const float* csup, const float* crep, float* af, float* wrep, float* wsup,
        const int* flag) {
    if (flag[0]) k3_body<1>(x, gate, csup, crep, af, wrep, wsup);
    else         k3_body<0>(x, gate, csup, crep, af, wrep, wsup);
}

// ---------------- kh1: hacc += fused @ Wf1 (split-K) ----------------
template<int F32> __device__ void kh1_body(const float* af, const float* wrep,
        const float* wsup, const void* Wf1, float* hacc, float* fs) {
    int tid = threadIdx.x;
    int c0 = blockIdx.x * 128, k0 = blockIdx.y * 144;
    for (int e = tid; e < 8 * 144; e += 256) {
        int b = e / 144, kk = e - b * 144;
        int k = k0 + kk;
        float v = (k < D) ? af[b * D + k] : (k < 2 * D) ? wrep[b * D + k - D]
                                                        : wsup[b * D + k - 2 * D];
        fs[b * 144 + kk] = v;
    }
    __syncthreads();
    int col = c0 + (tid & 127);
    int kg = tid >> 7;
    float acc[NB];
    #pragma unroll
    for (int b = 0; b < NB; ++b) acc[b] = 0.f;
    #pragma unroll 4
    for (int r = 0; r < 72; ++r) {
        int kk = kg * 72 + r;
        float w = ld1<F32>(Wf1, (size_t)(k0 + kk) * D + col);
        #pragma unroll
        for (int b = 0; b < NB; ++b) acc[b] += fs[b * 144 + kk] * w;
    }
    #pragma unroll
    for (int b = 0; b < NB; ++b) atomicAdd(&hacc[b * D + col], acc[b]);
}
__global__ __launch_bounds__(256) void kh1(const float* af, const float* wrep,
        const float* wsup, const void* Wf1, float* hacc, const int* flag) {
    __shared__ float fs[8 * 144];
    if (flag[0]) kh1_body<1>(af, wrep, wsup, Wf1, hacc, fs);
    else         kh1_body<0>(af, wrep, wsup, Wf1, hacc, fs);
}

// ---------------- kh2: oacc += relu(hacc+bf1) @ Wf2 (split-K) ----------------
template<int F32> __device__ void kh2_body(const float* hacc, const void* bf1,
        const void* Wf2, float* oacc, float* hsl) {
    int tid = threadIdx.x;
    int c0 = blockIdx.x * 128, k0 = blockIdx.y * 96;
    for (int e = tid; e < 8 * 96; e += 256) {
        int b = e / 96, kk = e - b * 96;
        int k = k0 + kk;
        hsl[b * 96 + kk] = fmaxf(hacc[b * D + k] + ld1<F32>(bf1, k), 0.f);
    }
    __syncthreads();
    int col = c0 + (tid & 127);
    int kg = tid >> 7;
    float acc[NB];
    #pragma unroll
    for (int b = 0; b < NB; ++b) acc[b] = 0.f;
    #pragma unroll 4
    for (int r = 0; r < 48; ++r) {
        int kk = kg * 48 + r;
        float w = ld1<F32>(Wf2, (size_t)(k0 + kk) * D + col);
        #pragma unroll
        for (int b = 0; b < NB; ++b) acc[b] += hsl[b * 96 + kk] * w;
    }
    #pragma unroll
    for (int b = 0; b < NB; ++b) atomicAdd(&oacc[b * D + col], acc[b]);
}
__global__ __launch_bounds__(256) void kh2(const float* hacc, const void* bf1,
        const void* Wf2, float* oacc, const int* flag) {
    __shared__ float hsl[8 * 96];
    if (flag[0]) kh2_body<1>(hacc, bf1, Wf2, oacc, hsl);
    else         kh2_body<0>(hacc, bf1, Wf2, oacc, hsl);
}

// ---------------- kln: out = LN(oacc + bf2) * gamma + beta ----------------
template<int F32> __device__ void kln_body(const float* oacc, const void* bf2,
        const void* gamma, const void* beta, void* out, float* red) {
    int b = blockIdx.x, tid = threadIdx.x;
    float o[3];
    #pragma unroll
    for (int u = 0; u < 3; ++u) {
        int i = tid + u * 256;
        o[u] = oacc[b * D + i] + ld1<F32>(bf2, i);
    }
    red[tid] = o[0] + o[1] + o[2]; __syncthreads();
    for (int s = 128; s > 0; s >>= 1) { if (tid < s) red[tid] += red[tid + s]; __syncthreads(); }
    float mu = red[0] / (float)D; __syncthreads();
    float vs = 0.f;
    #pragma unroll
    for (int u = 0; u < 3; ++u) vs += (o[u] - mu) * (o[u] - mu);
    red[tid] = vs; __syncthreads();
    for (int s = 128; s > 0; s >>= 1) { if (tid < s) red[tid] += red[tid + s]; __syncthreads(); }
    float var = red[0] / (float)D;
    float rstd = 1.0f / sqrtf(var + 1e-5f);
    #pragma unroll
    for (int u = 0; u < 3; ++u) {
        int i = tid + u * 256;
        float v = (o[u] - mu) * rstd * ld1<F32>(gamma, i) + ld1<F32>(beta, i);
        if (F32) ((float*)out)[b * D + i] = v;
        else     ((u16*)out)[b * D + i] = f2b(v);
    }
}
__global__ __launch_bounds__(256) void kln(const float* oacc, const void* bf2,
        const void* gamma, const void* beta, void* out, const int* flag) {
    __shared__ float red[256];
    if (flag[0]) kln_body<1>(oacc, bf2, gamma, beta, out, red);
    else         kln_body<0>(oacc, bf2, gamma, beta, out, red);
}

extern "C" void kernel_launch(void* const* d_in, const int* in_sizes, int n_in,
                              void* d_out, int out_size, void* d_ws, size_t ws_size,
                              hipStream_t stream) {
    const void* x    = d_in[0];
    const int* ids   = (const int*)d_in[1];
    const int* padp  = (const int*)d_in[2];
    const void* Wa   = d_in[3];
    const void* ba   = d_in[4];
    PP pp;
    pp.W[0] = d_in[5];  pp.b[0] = d_in[6];    // qs
    pp.W[1] = d_in[7];  pp.b[1] = d_in[8];    // ks
    pp.W[2] = d_in[9];  pp.b[2] = d_in[10];   // qc
    pp.W[3] = d_in[11]; pp.b[3] = d_in[12];   // kc
    pp.W[4] = d_in[13]; pp.b[4] = d_in[14];   // qr
    pp.W[5] = d_in[15]; pp.b[5] = d_in[16];   // kr
    const void* Wf1 = d_in[17]; const void* bf1 = d_in[18];
    const void* Wf2 = d_in[19]; const void* bf2 = d_in[20];
    const void* gamma = d_in[21]; const void* beta = d_in[22];

    char* ws = (char*)d_ws;
    int*   flag   = (int*)(ws + WS_FLAG);
    int*   sepArr = (int*)(ws + WS_SEP);
    float* c0   = (float*)(ws + WS_C0);
    float* z0   = (float*)(ws + WS_Z0);
    float* w1   = (float*)(ws + WS_W1);
    float* gate = (float*)(ws + WS_GATE);
    float* csup = (float*)(ws + WS_CSUP);
    float* crep = (float*)(ws + WS_CREP);
    float* af   = (float*)(ws + WS_AF);
    float* wrep = (float*)(ws + WS_WREP);
    float* wsup = (float*)(ws + WS_WSUP);
    float* hacc = (float*)(ws + WS_HACC);
    float* oacc = (float*)(ws + WS_OACC);
    float* alog = (float*)(ws + WS_ALOG);
    float* tbuf = (float*)(ws + WS_T);
    u16* xb   = (u16*)(ws + WS_XB);
    u16* Zbuf = (u16*)(ws + WS_Z);
    u16* Wb   = (u16*)(ws + WS_WB);
    u16* Mt   = (u16*)(ws + WS_M);
    u16* ssup = (u16*)(ws + WS_SSUP);
    u16* scmb = (u16*)(ws + WS_SCMB);

    kdetect<<<dim3(1), dim3(128), 0, stream>>>(x, ids, flag);
    kbias_row<<<dim3(12, 7), dim3(256), 0, stream>>>(pp, z0, w1, c0, flag);
    kx<<<dim3(1984), dim3(256), 0, stream>>>(x, pp, Wa, ba, w1, c0, xb, Wb, alog, tbuf, flag);
    k0b<<<dim3(NB), dim3(256), 0, stream>>>(ids, padp, alog, gate, sepArr,
                                            af, wrep, wsup, hacc, oacc, csup, crep, flag);
    kM_mfma<<<dim3(6, 6, 3), dim3(256), 0, stream>>>(Wb, Mt);
    kZ_mfma<<<dim3(6, 4, 24), dim3(256), 0, stream>>>(xb, Mt, z0, Zbuf, sepArr);
    kSsup_mfma<<<dim3(8, 4, NB), dim3(256), 0, stream>>>(Zbuf, xb, tbuf, sepArr, ssup);
    kScmb_mfma<<<dim3(8, 8, NB), dim3(256), 0, stream>>>(Zbuf, xb, tbuf, sepArr, scmb);
    k2bc<<<dim3(32, NB), dim3(256), 0, stream>>>(ssup, scmb, ids, padp, sepArr,
                                                 gate, csup, crep, flag);
    k3<<<dim3(64, NB), dim3(256), 0, stream>>>(x, gate, csup, crep, af, wrep, wsup, flag);
    kh1<<<dim3(6, 16), dim3(256), 0, stream>>>(af, wrep, wsup, Wf1, hacc, flag);
    kh2<<<dim3(6, 8), dim3(256), 0, stream>>>(hacc, bf1, Wf2, oacc, flag);
    kln<<<dim3(NB), dim3(256), 0, stream>>>(oacc, bf2, gamma, beta, d_out, flag);
}